// Round 1
// baseline (1958.999 us; speedup 1.0000x reference)
//
#include <hip/hip_runtime.h>
#include <math.h>

// ---------------------------------------------------------------------------
// FlashSVD LLaMA block, MI355X round 0: correctness-first bf16-MFMA pipeline.
// All GEMMs are C = A(bf16)[M,K] * B(fp32 weights -> bf16 on stage)[N,K]^T.
// ---------------------------------------------------------------------------

typedef __bf16 bf16;
typedef __bf16 bf16x8 __attribute__((ext_vector_type(8)));
typedef __bf16 bf16x4 __attribute__((ext_vector_type(4)));
typedef float  f32x4  __attribute__((ext_vector_type(4)));

#define EPI_BF16   0
#define EPI_BF16T  1   // transposed bf16 store (for V in [d][t] layout)
#define EPI_F32ADD 2   // fp32 store with residual add
#define EPI_SILU   3   // dual-acc: out = silu(acc1) * acc2, bf16 store

// ---------------------------------------------------------------------------
// Generic tiled MFMA GEMM: 128x128 tile, BK=32, 256 threads = 4 waves (2x2).
// A: bf16 [M,K] (lda, batch stride sA elements)
// B: fp32 [N,K] (ldb, batch stride sB) -- converted to bf16 during staging
// C: per-epilogue. grid = (M/128, N/128, batch)
// ---------------------------------------------------------------------------
template<int EPI>
__global__ __launch_bounds__(256)
void gemm_bt(const bf16* A, int lda, long sA,
             const float* B, int ldb, long sB,
             const bf16* A2, const float* B2,
             void* Cv, int ldc, long sC,
             const float* R, int K)
{
    constexpr bool DUAL = (EPI == EPI_SILU);
    // +8 bf16 pad -> 80B row stride (16B-aligned, breaks pow2 bank conflicts)
    __shared__ __align__(16) bf16 As [128][40];
    __shared__ __align__(16) bf16 Bs [128][40];
    __shared__ __align__(16) bf16 As2[DUAL ? 128 : 1][40];
    __shared__ __align__(16) bf16 Bs2[DUAL ? 128 : 1][40];

    const int tid  = threadIdx.x;
    const int lane = tid & 63;
    const int wid  = tid >> 6;
    const int wr   = wid >> 1, wc = wid & 1;     // 2x2 wave grid, each 64x64
    const int bm = blockIdx.x, bn = blockIdx.y, bz = blockIdx.z;

    const bf16*  Ab  = A + (long)bz * sA + (long)(bm * 128) * lda;
    const float* Bb  = B + (long)bz * sB + (long)(bn * 128) * ldb;
    const bf16*  Ab2 = DUAL ? (A2 + (long)(bm * 128) * lda) : nullptr;
    const float* Bb2 = DUAL ? (B2 + (long)(bn * 128) * ldb) : nullptr;

    f32x4 acc [4][4] = {};
    f32x4 acc2[DUAL ? 4 : 1][DUAL ? 4 : 1] = {};

    // staging coords: A = 128x32 bf16 (512 16B-chunks), B = 128x32 fp32
    const int a_r = tid >> 2, a_c = (tid & 3) * 8;
    const int b_r = tid >> 1, b_c = (tid & 1) * 16;
    const int g = lane >> 4, r = lane & 15;      // MFMA fragment coords

    for (int k0 = 0; k0 < K; k0 += 32) {
        __syncthreads();
        // stage A (bf16 passthrough)
        *(bf16x8*)&As[a_r][a_c]      = *(const bf16x8*)(Ab + (long)a_r * lda + k0 + a_c);
        *(bf16x8*)&As[a_r + 64][a_c] = *(const bf16x8*)(Ab + (long)(a_r + 64) * lda + k0 + a_c);
        // stage B (fp32 -> bf16 convert)
        {
            const float* s = Bb + (long)b_r * ldb + k0 + b_c;
            float4 f0 = ((const float4*)s)[0], f1 = ((const float4*)s)[1];
            float4 f2 = ((const float4*)s)[2], f3 = ((const float4*)s)[3];
            bf16x8 lo = {(bf16)f0.x,(bf16)f0.y,(bf16)f0.z,(bf16)f0.w,
                         (bf16)f1.x,(bf16)f1.y,(bf16)f1.z,(bf16)f1.w};
            bf16x8 hi = {(bf16)f2.x,(bf16)f2.y,(bf16)f2.z,(bf16)f2.w,
                         (bf16)f3.x,(bf16)f3.y,(bf16)f3.z,(bf16)f3.w};
            *(bf16x8*)&Bs[b_r][b_c]     = lo;
            *(bf16x8*)&Bs[b_r][b_c + 8] = hi;
        }
        if constexpr (DUAL) {
            *(bf16x8*)&As2[a_r][a_c]      = *(const bf16x8*)(Ab2 + (long)a_r * lda + k0 + a_c);
            *(bf16x8*)&As2[a_r + 64][a_c] = *(const bf16x8*)(Ab2 + (long)(a_r + 64) * lda + k0 + a_c);
            const float* s = Bb2 + (long)b_r * ldb + k0 + b_c;
            float4 f0 = ((const float4*)s)[0], f1 = ((const float4*)s)[1];
            float4 f2 = ((const float4*)s)[2], f3 = ((const float4*)s)[3];
            bf16x8 lo = {(bf16)f0.x,(bf16)f0.y,(bf16)f0.z,(bf16)f0.w,
                         (bf16)f1.x,(bf16)f1.y,(bf16)f1.z,(bf16)f1.w};
            bf16x8 hi = {(bf16)f2.x,(bf16)f2.y,(bf16)f2.z,(bf16)f2.w,
                         (bf16)f3.x,(bf16)f3.y,(bf16)f3.z,(bf16)f3.w};
            *(bf16x8*)&Bs2[b_r][b_c]     = lo;
            *(bf16x8*)&Bs2[b_r][b_c + 8] = hi;
        }
        __syncthreads();

        bf16x8 af[4], bfr[4];
        #pragma unroll
        for (int m = 0; m < 4; m++) af[m]  = *(const bf16x8*)&As[wr * 64 + m * 16 + r][g * 8];
        #pragma unroll
        for (int n = 0; n < 4; n++) bfr[n] = *(const bf16x8*)&Bs[wc * 64 + n * 16 + r][g * 8];
        #pragma unroll
        for (int m = 0; m < 4; m++)
            #pragma unroll
            for (int n = 0; n < 4; n++)
                acc[m][n] = __builtin_amdgcn_mfma_f32_16x16x32_bf16(af[m], bfr[n], acc[m][n], 0, 0, 0);

        if constexpr (DUAL) {
            bf16x8 af2[4], bfr2[4];
            #pragma unroll
            for (int m = 0; m < 4; m++) af2[m]  = *(const bf16x8*)&As2[wr * 64 + m * 16 + r][g * 8];
            #pragma unroll
            for (int n = 0; n < 4; n++) bfr2[n] = *(const bf16x8*)&Bs2[wc * 64 + n * 16 + r][g * 8];
            #pragma unroll
            for (int m = 0; m < 4; m++)
                #pragma unroll
                for (int n = 0; n < 4; n++)
                    acc2[m][n] = __builtin_amdgcn_mfma_f32_16x16x32_bf16(af2[m], bfr2[n], acc2[m][n], 0, 0, 0);
        }
    }

    // epilogue: C fragment layout (m89-verified): col = lane&15, row = (lane>>4)*4 + j
    #pragma unroll
    for (int m = 0; m < 4; m++) {
        #pragma unroll
        for (int n = 0; n < 4; n++) {
            const int row0 = bm * 128 + wr * 64 + m * 16 + g * 4;
            const int col  = bn * 128 + wc * 64 + n * 16 + r;
            #pragma unroll
            for (int j = 0; j < 4; j++) {
                float v = acc[m][n][j];
                long row = row0 + j;
                if constexpr (EPI == EPI_BF16) {
                    ((bf16*)Cv)[(long)bz * sC + row * (long)ldc + col] = (bf16)v;
                } else if constexpr (EPI == EPI_BF16T) {
                    ((bf16*)Cv)[(long)bz * sC + (long)col * ldc + row] = (bf16)v;
                } else if constexpr (EPI == EPI_F32ADD) {
                    long idx = row * (long)ldc + col;
                    ((float*)Cv)[idx] = v + R[idx];
                } else { // EPI_SILU
                    float a2 = acc2[m][n][j];
                    float sg = v / (1.f + __expf(-v));
                    ((bf16*)Cv)[row * (long)ldc + col] = (bf16)(sg * a2);
                }
            }
        }
    }
}

// ---------------------------------------------------------------------------
// RMSNorm: one block per row, D = 4096 fixed, fp32 in -> bf16 out.
// ---------------------------------------------------------------------------
__global__ __launch_bounds__(256)
void rmsnorm_k(const float* __restrict__ x, const float* __restrict__ w,
               bf16* __restrict__ out)
{
    const int D = 4096;
    const long row = blockIdx.x;
    const float* xr = x + row * D;
    float4 v[4];
    float ss = 0.f;
    #pragma unroll
    for (int k = 0; k < 4; k++) {
        v[k] = *(const float4*)&xr[threadIdx.x * 4 + k * 1024];
        ss += v[k].x * v[k].x + v[k].y * v[k].y + v[k].z * v[k].z + v[k].w * v[k].w;
    }
    #pragma unroll
    for (int o = 32; o > 0; o >>= 1) ss += __shfl_down(ss, o);
    __shared__ float red[4];
    if ((threadIdx.x & 63) == 0) red[threadIdx.x >> 6] = ss;
    __syncthreads();
    float rs = rsqrtf((red[0] + red[1] + red[2] + red[3]) / D + 1e-5f);
    #pragma unroll
    for (int k = 0; k < 4; k++) {
        int i = threadIdx.x * 4 + k * 1024;
        float4 wv = *(const float4*)&w[i];
        bf16x4 o4 = {(bf16)(v[k].x * rs * wv.x), (bf16)(v[k].y * rs * wv.y),
                     (bf16)(v[k].z * rs * wv.z), (bf16)(v[k].w * rs * wv.w)};
        *(bf16x4*)&out[row * D + i] = o4;
    }
}

// ---------------------------------------------------------------------------
// RoPE: reference = repeat_interleave(2) angles + rotate_half (split-half).
// cos/sin table [T][64] over angle index i; pair (d, d+64) uses i=d>>1, i+32.
// ---------------------------------------------------------------------------
__global__ __launch_bounds__(256)
void rope_table_k(float* cs, float* sn)
{
    int idx = blockIdx.x * blockDim.x + threadIdx.x;  // 1024*64
    int t = idx >> 6, i = idx & 63;
    float inv = powf(10000.0f, -(2.0f * i) / 128.0f);
    float a = (float)t * inv;
    cs[idx] = cosf(a);
    sn[idx] = sinf(a);
}

__global__ __launch_bounds__(256)
void rope_k(bf16* qk, const float* __restrict__ cs, const float* __restrict__ sn)
{
    // layout [nh][T=1024][128]; one thread per (head,t,d<64) pair, in-place safe
    long idx = (long)blockIdx.x * blockDim.x + threadIdx.x;
    int d = idx & 63;
    long ht = idx >> 6;
    int t = (int)(ht & 1023);
    bf16* p = qk + ht * 128;
    float x1 = (float)p[d], x2 = (float)p[d + 64];
    int i1 = d >> 1;
    float c1 = cs[t * 64 + i1],      s1 = sn[t * 64 + i1];
    float c2 = cs[t * 64 + 32 + i1], s2 = sn[t * 64 + 32 + i1];
    p[d]      = (bf16)(x1 * c1 - x2 * s1);
    p[d + 64] = (bf16)(x2 * c2 + x1 * s2);
}

// ---------------------------------------------------------------------------
// Flash attention (causal, GQA 4:1). Block = 4 waves; each wave owns 16 q-rows
// of a 64-row q-tile. K [hk][t][128] and V^T [hk][d][t] staged in LDS with
// 16B-chunk XOR swizzle (chunk ^= row&7) to break the 32-way D=128 conflict.
// ---------------------------------------------------------------------------
__global__ __launch_bounds__(256)
void attn_k(const bf16* __restrict__ Q,   // [32][1024][128] (rope'd)
            const bf16* __restrict__ Kb,  // [8][1024][128]  (rope'd)
            const bf16* __restrict__ Vt,  // [8][128][1024]
            bf16* __restrict__ O)         // [1024][4096] = [t][h*128+d]
{
    const int T = 1024;
    __shared__ __align__(16) bf16 Ks[64][128];   // row=kv t, 256B/row, swizzled
    __shared__ __align__(16) bf16 Vs[128][64];   // row=d,   128B/row, swizzled
    __shared__ __align__(16) bf16 Ps[4][16][72]; // per-wave P, +8 pad

    const int qt = blockIdx.x, h = blockIdx.y, hk = h >> 2;
    const int tid = threadIdx.x, lane = tid & 63, w = tid >> 6;
    const int g = lane >> 4, r = lane & 15;
    const int qrow0 = qt * 64 + w * 16;

    // Q fragments (held for the whole kernel): row = r, k-chunks over d
    bf16x8 qf[4];
    const bf16* qp = Q + ((long)h * T + qrow0 + r) * 128;
    #pragma unroll
    for (int dc = 0; dc < 4; dc++) qf[dc] = *(const bf16x8*)(qp + dc * 32 + g * 8);

    f32x4 o_acc[8] = {};
    float m_run[4], l_run[4];
    #pragma unroll
    for (int j = 0; j < 4; j++) { m_run[j] = -1e30f; l_run[j] = 0.f; }

    const float scale = 0.08838834764831845f;  // 1/sqrt(128)
    const int kv_end = qt * 64 + 64;

    for (int kv0 = 0; kv0 < kv_end; kv0 += 64) {
        __syncthreads();
        { // stage K tile: 64 rows x 16 chunks
            int tr = tid >> 2;
            const bf16* src = Kb + ((long)hk * T + kv0 + tr) * 128;
            #pragma unroll
            for (int q4 = 0; q4 < 4; q4++) {
                int c = (tid & 3) * 4 + q4;
                bf16x8 v = *(const bf16x8*)(src + c * 8);
                *(bf16x8*)&Ks[tr][(c ^ (tr & 7)) * 8] = v;
            }
        }
        { // stage V tile: 128 rows(d) x 8 chunks
            int dd = tid >> 1;
            const bf16* src = Vt + ((long)hk * 128 + dd) * T + kv0;
            #pragma unroll
            for (int q4 = 0; q4 < 4; q4++) {
                int c = (tid & 1) * 4 + q4;
                bf16x8 v = *(const bf16x8*)(src + c * 8);
                *(bf16x8*)&Vs[dd][(c ^ (dd & 7)) * 8] = v;
            }
        }
        __syncthreads();

        // S = Q K^T for this wave's 16 q-rows x 64 kv
        f32x4 s[4] = {};
        #pragma unroll
        for (int n = 0; n < 4; n++) {
            int tr = n * 16 + r;
            #pragma unroll
            for (int dc = 0; dc < 4; dc++) {
                int c = (dc * 4 + g) ^ (tr & 7);
                bf16x8 kf = *(const bf16x8*)&Ks[tr][c * 8];
                s[n] = __builtin_amdgcn_mfma_f32_16x16x32_bf16(qf[dc], kf, s[n], 0, 0, 0);
            }
        }

        // online softmax (rows live in j; 16-lane groups share a row)
        #pragma unroll
        for (int j = 0; j < 4; j++) {
            int qpos = qrow0 + g * 4 + j;
            float mx = m_run[j];
            #pragma unroll
            for (int n = 0; n < 4; n++) {
                int kpos = kv0 + n * 16 + r;
                float sv = s[n][j] * scale;
                sv = (kpos <= qpos) ? sv : -1e30f;
                s[n][j] = sv;
                mx = fmaxf(mx, sv);
            }
            #pragma unroll
            for (int mask = 1; mask < 16; mask <<= 1) mx = fmaxf(mx, __shfl_xor(mx, mask));
            float corr = __expf(m_run[j] - mx);
            l_run[j] *= corr;
            #pragma unroll
            for (int db = 0; db < 8; db++) o_acc[db][j] *= corr;
            float ls = 0.f;
            #pragma unroll
            for (int n = 0; n < 4; n++) {
                float p = __expf(s[n][j] - mx);
                s[n][j] = p;
                ls += p;
            }
            #pragma unroll
            for (int mask = 1; mask < 16; mask <<= 1) ls += __shfl_xor(ls, mask);
            l_run[j] += ls;
            m_run[j] = mx;
        }

        // P -> per-wave LDS (A-operand layout for PV)
        #pragma unroll
        for (int n = 0; n < 4; n++)
            #pragma unroll
            for (int j = 0; j < 4; j++)
                Ps[w][g * 4 + j][n * 16 + r] = (bf16)s[n][j];
        __syncthreads();

        bf16x8 pf[2];
        #pragma unroll
        for (int kc = 0; kc < 2; kc++)
            pf[kc] = *(const bf16x8*)&Ps[w][r][kc * 32 + g * 8];
        #pragma unroll
        for (int db = 0; db < 8; db++) {
            #pragma unroll
            for (int kc = 0; kc < 2; kc++) {
                int dd = db * 16 + r;
                int c = (kc * 4 + g) ^ (dd & 7);
                bf16x8 vf = *(const bf16x8*)&Vs[dd][c * 8];
                o_acc[db] = __builtin_amdgcn_mfma_f32_16x16x32_bf16(pf[kc], vf, o_acc[db], 0, 0, 0);
            }
        }
    }

    // normalize and store: O[t][h*128 + d]
    #pragma unroll
    for (int db = 0; db < 8; db++) {
        #pragma unroll
        for (int j = 0; j < 4; j++) {
            int t = qrow0 + g * 4 + j;
            float v = o_acc[db][j] / l_run[j];
            O[(long)t * 4096 + h * 128 + db * 16 + r] = (bf16)v;
        }
    }
}

// ---------------------------------------------------------------------------
extern "C" void kernel_launch(void* const* d_in, const int* in_sizes, int n_in,
                              void* d_out, int out_size, void* d_ws, size_t ws_size,
                              hipStream_t stream)
{
    const float* X   = (const float*)d_in[0];
    const float* LN1 = (const float*)d_in[1];
    const float* LN2 = (const float*)d_in[2];
    const float* qUs = (const float*)d_in[3];
    const float* qV  = (const float*)d_in[4];
    const float* kUs = (const float*)d_in[5];
    const float* kV  = (const float*)d_in[6];
    const float* vUs = (const float*)d_in[7];
    const float* vV  = (const float*)d_in[8];
    const float* oUs = (const float*)d_in[9];
    const float* oV  = (const float*)d_in[10];
    const float* gUs = (const float*)d_in[11];
    const float* gV  = (const float*)d_in[12];
    const float* uUs = (const float*)d_in[13];
    const float* uV  = (const float*)d_in[14];
    const float* dUs = (const float*)d_in[15];
    const float* dV  = (const float*)d_in[16];
    float* OUT = (float*)d_out;   // also holds x2 residual between phases

    char* w = (char*)d_ws;        // peak use ~44 MB (MLP phase aliases attn phase)
    bf16*  h1   = (bf16*)(w + 0);          // [1024,4096]
    bf16*  xrq  = (bf16*)(w + 8388608);    // [1024,2048]
    bf16*  xrk  = (bf16*)(w + 12582912);   // [1024,512]
    bf16*  xrv  = (bf16*)(w + 13631488);   // [1024,512]
    bf16*  qb   = (bf16*)(w + 14680064);   // [32,1024,128]
    bf16*  kb   = (bf16*)(w + 23068672);   // [8,1024,128]
    bf16*  vt   = (bf16*)(w + 25165824);   // [8,128,1024]
    float* cs   = (float*)(w + 27262976);  // [1024,64]
    float* sn   = (float*)(w + 27525120);  // [1024,64]
    bf16*  att  = (bf16*)(w + 27787264);   // [1024,4096]
    bf16*  r1   = (bf16*)(w + 36175872);   // [1024,1024]
    // MLP phase (attn buffers dead by then):
    bf16*  h2   = (bf16*)(w + 0);          // [1024,4096]
    bf16*  gr   = (bf16*)(w + 8388608);    // [1024,1024]
    bf16*  ur   = (bf16*)(w + 10485760);   // [1024,1024]
    bf16*  hmid = (bf16*)(w + 12582912);   // [1024,14336]
    bf16*  dr   = (bf16*)(w + 41943040);   // [1024,1024]

    dim3 blk(256);

    // --- attention half ---
    rmsnorm_k<<<1024, blk, 0, stream>>>(X, LN1, h1);
    gemm_bt<EPI_BF16 ><<<dim3(8,16,1), blk, 0, stream>>>(h1,4096,0, qV,4096,0, nullptr,nullptr, xrq,2048,0, nullptr, 4096);
    gemm_bt<EPI_BF16 ><<<dim3(8, 4,1), blk, 0, stream>>>(h1,4096,0, kV,4096,0, nullptr,nullptr, xrk, 512,0, nullptr, 4096);
    gemm_bt<EPI_BF16 ><<<dim3(8, 4,1), blk, 0, stream>>>(h1,4096,0, vV,4096,0, nullptr,nullptr, xrv, 512,0, nullptr, 4096);
    gemm_bt<EPI_BF16 ><<<dim3(8, 1,32),blk, 0, stream>>>(xrq,2048,64, qUs,64,8192, nullptr,nullptr, qb,128,131072, nullptr, 64);
    gemm_bt<EPI_BF16 ><<<dim3(8, 1, 8),blk, 0, stream>>>(xrk, 512,64, kUs,64,8192, nullptr,nullptr, kb,128,131072, nullptr, 64);
    gemm_bt<EPI_BF16T><<<dim3(8, 1, 8),blk, 0, stream>>>(xrv, 512,64, vUs,64,8192, nullptr,nullptr, vt,1024,131072, nullptr, 64);
    rope_table_k<<<256, blk, 0, stream>>>(cs, sn);
    rope_k<<<8192, blk, 0, stream>>>(qb, cs, sn);   // 32*1024*64 pairs
    rope_k<<<2048, blk, 0, stream>>>(kb, cs, sn);   //  8*1024*64 pairs
    attn_k<<<dim3(16,32), blk, 0, stream>>>(qb, kb, vt, att);
    gemm_bt<EPI_BF16  ><<<dim3(8, 8,1), blk, 0, stream>>>(att,4096,0, oV,4096,0, nullptr,nullptr, r1,1024,0, nullptr, 4096);
    gemm_bt<EPI_F32ADD><<<dim3(8,32,1), blk, 0, stream>>>(r1,1024,0, oUs,1024,0, nullptr,nullptr, OUT,4096,0, X, 1024);

    // --- MLP half ---
    rmsnorm_k<<<1024, blk, 0, stream>>>(OUT, LN2, h2);
    gemm_bt<EPI_BF16  ><<<dim3(8,  8,1), blk, 0, stream>>>(h2,4096,0, gV,4096,0, nullptr,nullptr, gr,1024,0, nullptr, 4096);
    gemm_bt<EPI_BF16  ><<<dim3(8,  8,1), blk, 0, stream>>>(h2,4096,0, uV,4096,0, nullptr,nullptr, ur,1024,0, nullptr, 4096);
    gemm_bt<EPI_SILU  ><<<dim3(8,112,1), blk, 0, stream>>>(gr,1024,0, gUs,1024,0, ur, uUs, hmid,14336,0, nullptr, 1024);
    gemm_bt<EPI_BF16  ><<<dim3(8,  8,1), blk, 0, stream>>>(hmid,14336,0, dV,14336,0, nullptr,nullptr, dr,1024,0, nullptr, 14336);
    gemm_bt<EPI_F32ADD><<<dim3(8, 32,1), blk, 0, stream>>>(dr,1024,0, dUs,1024,0, nullptr,nullptr, OUT,4096,0, OUT, 1024);
}

// Round 2
// 822.470 us; speedup vs baseline: 2.3818x; 2.3818x over previous
//
#include <hip/hip_runtime.h>
#include <math.h>

// ---------------------------------------------------------------------------
// FlashSVD LLaMA block, round 2: split-K everywhere grids were tiny (the
// profiled killer: 64-block GEMMs at 3% occupancy), conflict-free XOR-swizzled
// LDS staging, deterministic fp32-partial + reduce (no atomics).
// ---------------------------------------------------------------------------

typedef __bf16 bf16;
typedef __bf16 bf16x8 __attribute__((ext_vector_type(8)));
typedef __bf16 bf16x4 __attribute__((ext_vector_type(4)));
typedef float  f32x4  __attribute__((ext_vector_type(4)));

#define EPI_BF16   0
#define EPI_BF16T  1   // transposed bf16 store (V in [d][t] layout)
#define EPI_F32ADD 2   // fp32 store with residual add
#define EPI_SILU   3   // dual-acc: out = silu(acc1) * acc2, bf16 store
#define EPI_PART   4   // fp32 partial plane store (split-K)

// ---------------------------------------------------------------------------
// Tiled MFMA GEMM: 128x128 tile, BK=32, 256 threads = 4 waves (2x2).
// A: bf16 [M,K]; B: fp32 [N,K] -> bf16 on stage.  C per epilogue.
// grid.z = batch * nsplit (split-K chunks of Kc).  For EPI_PART with B2 set,
// zb=bz/nsplit in {0,1} selects B vs B2 (two GEMMs sharing A, batched).
// LDS: padless [128][32] per tile, 16B chunks XOR-swizzled by (row&3):
// both staging writes and ds_read_b128 fragment reads are bank-ideal.
// ---------------------------------------------------------------------------
template<int EPI>
__global__ __launch_bounds__(256)
void gemm_bt(const bf16* A, int lda, long sA,
             const float* B, int ldb, long sB,
             const bf16* A2, const float* B2,
             void* Cv, int ldc, long sC,
             const float* R, int Kc, int nsplit)
{
    constexpr bool DUAL = (EPI == EPI_SILU);
    __shared__ __align__(16) bf16 As [128 * 32];
    __shared__ __align__(16) bf16 Bs [128 * 32];
    __shared__ __align__(16) bf16 As2[DUAL ? 128 * 32 : 8];
    __shared__ __align__(16) bf16 Bs2[DUAL ? 128 * 32 : 8];

    const int tid  = threadIdx.x;
    const int lane = tid & 63;
    const int wid  = tid >> 6;
    const int wr   = wid >> 1, wc = wid & 1;     // 2x2 wave grid, each 64x64
    const int bm = blockIdx.x, bn = blockIdx.y, bz = blockIdx.z;
    const int ks = bz % nsplit, zb = bz / nsplit;

    const float* Bsel = (EPI == EPI_PART && B2 != nullptr && zb) ? B2 : B;
    const bf16*  Ab  = A    + (long)zb * sA + (long)(bm * 128) * lda + (long)ks * Kc;
    const float* Bb  = Bsel + (long)zb * sB + (long)(bn * 128) * ldb + (long)ks * Kc;
    const bf16*  Ab2 = DUAL ? (A2 + (long)(bm * 128) * lda) : nullptr;
    const float* Bb2 = DUAL ? (B2 + (long)(bn * 128) * ldb) : nullptr;

    f32x4 acc [4][4] = {};
    f32x4 acc2[DUAL ? 4 : 1][DUAL ? 4 : 1] = {};

    // staging coords
    const int ar = tid >> 2, ac = tid & 3;       // A: 4 lanes/row, 16B chunks
    const int br = tid >> 3, bc = tid & 7;       // B: 8 lanes/row, float4 each
    const int g = lane >> 4, r = lane & 15;      // MFMA fragment coords

    for (int k0 = 0; k0 < Kc; k0 += 32) {
        __syncthreads();
        #pragma unroll
        for (int p = 0; p < 2; p++) {            // A tile 128x32 bf16
            int row = ar + p * 64;
            bf16x8 v = *(const bf16x8*)(Ab + (long)row * lda + k0 + ac * 8);
            *(bf16x8*)&As[row * 32 + ((ac ^ (row & 3)) * 8)] = v;
        }
        #pragma unroll
        for (int p = 0; p < 4; p++) {            // B tile 128x32 fp32 -> bf16
            int row = br + p * 32;
            float4 f = *(const float4*)(Bb + (long)row * ldb + k0 + bc * 4);
            bf16x4 h = {(bf16)f.x, (bf16)f.y, (bf16)f.z, (bf16)f.w};
            *(bf16x4*)&Bs[row * 32 + (((bc >> 1) ^ (row & 3)) * 8) + (bc & 1) * 4] = h;
        }
        if constexpr (DUAL) {
            #pragma unroll
            for (int p = 0; p < 2; p++) {
                int row = ar + p * 64;
                bf16x8 v = *(const bf16x8*)(Ab2 + (long)row * lda + k0 + ac * 8);
                *(bf16x8*)&As2[row * 32 + ((ac ^ (row & 3)) * 8)] = v;
            }
            #pragma unroll
            for (int p = 0; p < 4; p++) {
                int row = br + p * 32;
                float4 f = *(const float4*)(Bb2 + (long)row * ldb + k0 + bc * 4);
                bf16x4 h = {(bf16)f.x, (bf16)f.y, (bf16)f.z, (bf16)f.w};
                *(bf16x4*)&Bs2[row * 32 + (((bc >> 1) ^ (row & 3)) * 8) + (bc & 1) * 4] = h;
            }
        }
        __syncthreads();

        bf16x8 af[4], bfr[4];
        #pragma unroll
        for (int m = 0; m < 4; m++) {
            int row = wr * 64 + m * 16 + r;
            af[m] = *(const bf16x8*)&As[row * 32 + ((g ^ (row & 3)) * 8)];
        }
        #pragma unroll
        for (int n = 0; n < 4; n++) {
            int row = wc * 64 + n * 16 + r;
            bfr[n] = *(const bf16x8*)&Bs[row * 32 + ((g ^ (row & 3)) * 8)];
        }
        #pragma unroll
        for (int m = 0; m < 4; m++)
            #pragma unroll
            for (int n = 0; n < 4; n++)
                acc[m][n] = __builtin_amdgcn_mfma_f32_16x16x32_bf16(af[m], bfr[n], acc[m][n], 0, 0, 0);

        if constexpr (DUAL) {
            bf16x8 af2[4], bfr2[4];
            #pragma unroll
            for (int m = 0; m < 4; m++) {
                int row = wr * 64 + m * 16 + r;
                af2[m] = *(const bf16x8*)&As2[row * 32 + ((g ^ (row & 3)) * 8)];
            }
            #pragma unroll
            for (int n = 0; n < 4; n++) {
                int row = wc * 64 + n * 16 + r;
                bfr2[n] = *(const bf16x8*)&Bs2[row * 32 + ((g ^ (row & 3)) * 8)];
            }
            #pragma unroll
            for (int m = 0; m < 4; m++)
                #pragma unroll
                for (int n = 0; n < 4; n++)
                    acc2[m][n] = __builtin_amdgcn_mfma_f32_16x16x32_bf16(af2[m], bfr2[n], acc2[m][n], 0, 0, 0);
        }
    }

    // epilogue: C fragment layout: col = lane&15, row = (lane>>4)*4 + j
    #pragma unroll
    for (int m = 0; m < 4; m++) {
        #pragma unroll
        for (int n = 0; n < 4; n++) {
            const int row0 = bm * 128 + wr * 64 + m * 16 + g * 4;
            const int col  = bn * 128 + wc * 64 + n * 16 + r;
            #pragma unroll
            for (int j = 0; j < 4; j++) {
                float v = acc[m][n][j];
                long row = row0 + j;
                if constexpr (EPI == EPI_BF16) {
                    ((bf16*)Cv)[(long)zb * sC + row * (long)ldc + col] = (bf16)v;
                } else if constexpr (EPI == EPI_BF16T) {
                    ((bf16*)Cv)[(long)zb * sC + (long)col * ldc + row] = (bf16)v;
                } else if constexpr (EPI == EPI_F32ADD) {
                    long idx = row * (long)ldc + col;
                    ((float*)Cv)[idx] = v + R[idx];
                } else if constexpr (EPI == EPI_PART) {
                    ((float*)Cv)[(long)bz * sC + row * (long)ldc + col] = v;
                } else { // EPI_SILU
                    float a2 = acc2[m][n][j];
                    float sg = v / (1.f + __expf(-v));
                    ((bf16*)Cv)[row * (long)ldc + col] = (bf16)(sg * a2);
                }
            }
        }
    }
}

// ---------------------------------------------------------------------------
// Split-K reduction: sum np fp32 planes of pe elements -> bf16.
// ---------------------------------------------------------------------------
__global__ __launch_bounds__(256)
void reduce_k(const float* __restrict__ part, long pe, int np, bf16* __restrict__ out)
{
    long i = ((long)blockIdx.x * 256 + threadIdx.x) * 4;
    float4 s = *(const float4*)&part[i];
    for (int p = 1; p < np; p++) {
        float4 v = *(const float4*)&part[(long)p * pe + i];
        s.x += v.x; s.y += v.y; s.z += v.z; s.w += v.w;
    }
    bf16x4 o = {(bf16)s.x, (bf16)s.y, (bf16)s.z, (bf16)s.w};
    *(bf16x4*)&out[i] = o;
}

// ---------------------------------------------------------------------------
// RMSNorm: one block per row, D = 4096, fp32 in -> bf16 out.
// ---------------------------------------------------------------------------
__global__ __launch_bounds__(256)
void rmsnorm_k(const float* __restrict__ x, const float* __restrict__ w,
               bf16* __restrict__ out)
{
    const int D = 4096;
    const long row = blockIdx.x;
    const float* xr = x + row * D;
    float4 v[4];
    float ss = 0.f;
    #pragma unroll
    for (int k = 0; k < 4; k++) {
        v[k] = *(const float4*)&xr[threadIdx.x * 4 + k * 1024];
        ss += v[k].x * v[k].x + v[k].y * v[k].y + v[k].z * v[k].z + v[k].w * v[k].w;
    }
    #pragma unroll
    for (int o = 32; o > 0; o >>= 1) ss += __shfl_down(ss, o);
    __shared__ float red[4];
    if ((threadIdx.x & 63) == 0) red[threadIdx.x >> 6] = ss;
    __syncthreads();
    float rs = rsqrtf((red[0] + red[1] + red[2] + red[3]) / D + 1e-5f);
    #pragma unroll
    for (int k = 0; k < 4; k++) {
        int i = threadIdx.x * 4 + k * 1024;
        float4 wv = *(const float4*)&w[i];
        bf16x4 o4 = {(bf16)(v[k].x * rs * wv.x), (bf16)(v[k].y * rs * wv.y),
                     (bf16)(v[k].z * rs * wv.z), (bf16)(v[k].w * rs * wv.w)};
        *(bf16x4*)&out[row * D + i] = o4;
    }
}

// ---------------------------------------------------------------------------
// RoPE (repeat_interleave(2) angles + rotate_half split-half convention).
// ---------------------------------------------------------------------------
__global__ __launch_bounds__(256)
void rope_table_k(float* cs, float* sn)
{
    int idx = blockIdx.x * blockDim.x + threadIdx.x;  // 1024*64
    int t = idx >> 6, i = idx & 63;
    float inv = powf(10000.0f, -(2.0f * i) / 128.0f);
    float a = (float)t * inv;
    cs[idx] = cosf(a);
    sn[idx] = sinf(a);
}

__global__ __launch_bounds__(256)
void rope_k(bf16* qk, const float* __restrict__ cs, const float* __restrict__ sn)
{
    long idx = (long)blockIdx.x * blockDim.x + threadIdx.x;
    int d = idx & 63;
    long ht = idx >> 6;
    int t = (int)(ht & 1023);
    bf16* p = qk + ht * 128;
    float x1 = (float)p[d], x2 = (float)p[d + 64];
    int i1 = d >> 1;
    float c1 = cs[t * 64 + i1],      s1 = sn[t * 64 + i1];
    float c2 = cs[t * 64 + 32 + i1], s2 = sn[t * 64 + 32 + i1];
    p[d]      = (bf16)(x1 * c1 - x2 * s1);
    p[d + 64] = (bf16)(x2 * c2 + x1 * s2);
}

// ---------------------------------------------------------------------------
// Flash attention (causal, GQA 4:1), 4 waves x 16 q-rows, KV tile 64.
// ---------------------------------------------------------------------------
__global__ __launch_bounds__(256)
void attn_k(const bf16* __restrict__ Q,   // [32][1024][128]
            const bf16* __restrict__ Kb,  // [8][1024][128]
            const bf16* __restrict__ Vt,  // [8][128][1024]
            bf16* __restrict__ O)         // [1024][4096]
{
    const int T = 1024;
    __shared__ __align__(16) bf16 Ks[64][128];
    __shared__ __align__(16) bf16 Vs[128][64];
    __shared__ __align__(16) bf16 Ps[4][16][72];

    const int qt = blockIdx.x, h = blockIdx.y, hk = h >> 2;
    const int tid = threadIdx.x, lane = tid & 63, w = tid >> 6;
    const int g = lane >> 4, r = lane & 15;
    const int qrow0 = qt * 64 + w * 16;

    bf16x8 qf[4];
    const bf16* qp = Q + ((long)h * T + qrow0 + r) * 128;
    #pragma unroll
    for (int dc = 0; dc < 4; dc++) qf[dc] = *(const bf16x8*)(qp + dc * 32 + g * 8);

    f32x4 o_acc[8] = {};
    float m_run[4], l_run[4];
    #pragma unroll
    for (int j = 0; j < 4; j++) { m_run[j] = -1e30f; l_run[j] = 0.f; }

    const float scale = 0.08838834764831845f;
    const int kv_end = qt * 64 + 64;

    for (int kv0 = 0; kv0 < kv_end; kv0 += 64) {
        __syncthreads();
        {
            int tr = tid >> 2;
            const bf16* src = Kb + ((long)hk * T + kv0 + tr) * 128;
            #pragma unroll
            for (int q4 = 0; q4 < 4; q4++) {
                int c = (tid & 3) * 4 + q4;
                bf16x8 v = *(const bf16x8*)(src + c * 8);
                *(bf16x8*)&Ks[tr][(c ^ (tr & 7)) * 8] = v;
            }
        }
        {
            int dd = tid >> 1;
            const bf16* src = Vt + ((long)hk * 128 + dd) * T + kv0;
            #pragma unroll
            for (int q4 = 0; q4 < 4; q4++) {
                int c = (tid & 1) * 4 + q4;
                bf16x8 v = *(const bf16x8*)(src + c * 8);
                *(bf16x8*)&Vs[dd][(c ^ (dd & 7)) * 8] = v;
            }
        }
        __syncthreads();

        f32x4 s[4] = {};
        #pragma unroll
        for (int n = 0; n < 4; n++) {
            int tr = n * 16 + r;
            #pragma unroll
            for (int dc = 0; dc < 4; dc++) {
                int c = (dc * 4 + g) ^ (tr & 7);
                bf16x8 kf = *(const bf16x8*)&Ks[tr][c * 8];
                s[n] = __builtin_amdgcn_mfma_f32_16x16x32_bf16(qf[dc], kf, s[n], 0, 0, 0);
            }
        }

        #pragma unroll
        for (int j = 0; j < 4; j++) {
            int qpos = qrow0 + g * 4 + j;
            float mx = m_run[j];
            #pragma unroll
            for (int n = 0; n < 4; n++) {
                int kpos = kv0 + n * 16 + r;
                float sv = s[n][j] * scale;
                sv = (kpos <= qpos) ? sv : -1e30f;
                s[n][j] = sv;
                mx = fmaxf(mx, sv);
            }
            #pragma unroll
            for (int mask = 1; mask < 16; mask <<= 1) mx = fmaxf(mx, __shfl_xor(mx, mask));
            float corr = __expf(m_run[j] - mx);
            l_run[j] *= corr;
            #pragma unroll
            for (int db = 0; db < 8; db++) o_acc[db][j] *= corr;
            float ls = 0.f;
            #pragma unroll
            for (int n = 0; n < 4; n++) {
                float p = __expf(s[n][j] - mx);
                s[n][j] = p;
                ls += p;
            }
            #pragma unroll
            for (int mask = 1; mask < 16; mask <<= 1) ls += __shfl_xor(ls, mask);
            l_run[j] += ls;
            m_run[j] = mx;
        }

        #pragma unroll
        for (int n = 0; n < 4; n++)
            #pragma unroll
            for (int j = 0; j < 4; j++)
                Ps[w][g * 4 + j][n * 16 + r] = (bf16)s[n][j];
        __syncthreads();

        bf16x8 pf[2];
        #pragma unroll
        for (int kc = 0; kc < 2; kc++)
            pf[kc] = *(const bf16x8*)&Ps[w][r][kc * 32 + g * 8];
        #pragma unroll
        for (int db = 0; db < 8; db++) {
            #pragma unroll
            for (int kc = 0; kc < 2; kc++) {
                int dd = db * 16 + r;
                int c = (kc * 4 + g) ^ (dd & 7);
                bf16x8 vf = *(const bf16x8*)&Vs[dd][c * 8];
                o_acc[db] = __builtin_amdgcn_mfma_f32_16x16x32_bf16(pf[kc], vf, o_acc[db], 0, 0, 0);
            }
        }
    }

    #pragma unroll
    for (int db = 0; db < 8; db++) {
        #pragma unroll
        for (int j = 0; j < 4; j++) {
            int t = qrow0 + g * 4 + j;
            float v = o_acc[db][j] / l_run[j];
            O[(long)t * 4096 + h * 128 + db * 16 + r] = (bf16)v;
        }
    }
}

// ---------------------------------------------------------------------------
extern "C" void kernel_launch(void* const* d_in, const int* in_sizes, int n_in,
                              void* d_out, int out_size, void* d_ws, size_t ws_size,
                              hipStream_t stream)
{
    const float* X   = (const float*)d_in[0];
    const float* LN1 = (const float*)d_in[1];
    const float* LN2 = (const float*)d_in[2];
    const float* qUs = (const float*)d_in[3];
    const float* qV  = (const float*)d_in[4];
    const float* kUs = (const float*)d_in[5];
    const float* kV  = (const float*)d_in[6];
    const float* vUs = (const float*)d_in[7];
    const float* vV  = (const float*)d_in[8];
    const float* oUs = (const float*)d_in[9];
    const float* oV  = (const float*)d_in[10];
    const float* gUs = (const float*)d_in[11];
    const float* gV  = (const float*)d_in[12];
    const float* uUs = (const float*)d_in[13];
    const float* uV  = (const float*)d_in[14];
    const float* dUs = (const float*)d_in[15];
    const float* dV  = (const float*)d_in[16];
    float* OUT = (float*)d_out;

    char* w = (char*)d_ws;
    bf16*  h1   = (bf16*)(w + 0);          // [1024,4096]
    bf16*  xrq  = (bf16*)(w + 8388608);    // [1024,2048]
    bf16*  xrk  = (bf16*)(w + 12582912);   // [1024,512]
    bf16*  xrv  = (bf16*)(w + 13631488);   // [1024,512]
    bf16*  qb   = (bf16*)(w + 14680064);   // [32,1024,128]
    bf16*  kb   = (bf16*)(w + 23068672);   // [8,1024,128]
    bf16*  vt   = (bf16*)(w + 25165824);   // [8,128,1024]
    float* cs   = (float*)(w + 27262976);  // [1024,64]
    float* sn   = (float*)(w + 27525120);  // [1024,64]
    bf16*  att  = (bf16*)(w + 27787264);   // [1024,4096]
    bf16*  r1   = (bf16*)(w + 36175872);   // [1024,1024]
    // MLP phase aliases (attn intermediates dead by then)
    bf16*  h2   = (bf16*)(w + 0);          // [1024,4096]
    bf16*  gr   = (bf16*)(w + 8388608);    // [1024,1024]
    bf16*  ur   = (bf16*)(w + 10485760);   // [1024,1024]
    bf16*  hmid = (bf16*)(w + 12582912);   // [1024,14336]
    bf16*  dr   = (bf16*)(w + 41943040);   // [1024,1024]
    // split-K partial arena (transient between gemm and reduce)
    const size_t ARENA = 44040192;
    float* part = (float*)(w + ARENA);
    const bool big = ws_size >= (size_t)(ARENA + 8L * 1048576 * 4);  // 8 planes x 1M fp32

    dim3 blk(256);

    rmsnorm_k<<<1024, blk, 0, stream>>>(X, LN1, h1);

    if (big) {
        // xr_q: K=4096 split 2 -> 256 blocks
        gemm_bt<EPI_PART><<<dim3(8,16,2), blk, 0, stream>>>(h1,4096,0, qV,4096,0, nullptr,nullptr, part,2048,2097152, nullptr, 2048, 2);
        reduce_k<<<2048, blk, 0, stream>>>(part, 2097152, 2, xrq);
        // xr_k + xr_v batched (share A=h1), K=4096 split 4 -> 256 blocks
        gemm_bt<EPI_PART><<<dim3(8,4,8), blk, 0, stream>>>(h1,4096,0, kV,4096,0, nullptr,vV, part,512,524288, nullptr, 1024, 4);
        reduce_k<<<512, blk, 0, stream>>>(part,               524288, 4, xrk);
        reduce_k<<<512, blk, 0, stream>>>(part + 4L*524288,   524288, 4, xrv);
    } else {
        gemm_bt<EPI_BF16><<<dim3(8,16,1), blk, 0, stream>>>(h1,4096,0, qV,4096,0, nullptr,nullptr, xrq,2048,0, nullptr, 4096, 1);
        gemm_bt<EPI_BF16><<<dim3(8, 4,1), blk, 0, stream>>>(h1,4096,0, kV,4096,0, nullptr,nullptr, xrk, 512,0, nullptr, 4096, 1);
        gemm_bt<EPI_BF16><<<dim3(8, 4,1), blk, 0, stream>>>(h1,4096,0, vV,4096,0, nullptr,nullptr, xrv, 512,0, nullptr, 4096, 1);
    }

    gemm_bt<EPI_BF16 ><<<dim3(8,1,32), blk, 0, stream>>>(xrq,2048,64, qUs,64,8192, nullptr,nullptr, qb,128,131072, nullptr, 64, 1);
    gemm_bt<EPI_BF16 ><<<dim3(8,1, 8), blk, 0, stream>>>(xrk, 512,64, kUs,64,8192, nullptr,nullptr, kb,128,131072, nullptr, 64, 1);
    gemm_bt<EPI_BF16T><<<dim3(8,1, 8), blk, 0, stream>>>(xrv, 512,64, vUs,64,8192, nullptr,nullptr, vt,1024,131072, nullptr, 64, 1);
    rope_table_k<<<256, blk, 0, stream>>>(cs, sn);
    rope_k<<<8192, blk, 0, stream>>>(qb, cs, sn);
    rope_k<<<2048, blk, 0, stream>>>(kb, cs, sn);
    attn_k<<<dim3(16,32), blk, 0, stream>>>(qb, kb, vt, att);

    if (big) {
        // attn @ oV^T: K=4096 split 4 -> 256 blocks
        gemm_bt<EPI_PART><<<dim3(8,8,4), blk, 0, stream>>>(att,4096,0, oV,4096,0, nullptr,nullptr, part,1024,1048576, nullptr, 1024, 4);
        reduce_k<<<1024, blk, 0, stream>>>(part, 1048576, 4, r1);
    } else {
        gemm_bt<EPI_BF16><<<dim3(8,8,1), blk, 0, stream>>>(att,4096,0, oV,4096,0, nullptr,nullptr, r1,1024,0, nullptr, 4096, 1);
    }
    gemm_bt<EPI_F32ADD><<<dim3(8,32,1), blk, 0, stream>>>(r1,1024,0, oUs,1024,0, nullptr,nullptr, OUT,4096,0, X, 1024, 1);

    // --- MLP half ---
    rmsnorm_k<<<1024, blk, 0, stream>>>(OUT, LN2, h2);
    if (big) {
        // g_r + u_r batched (share A=h2), K=4096 split 4 -> 512 blocks
        gemm_bt<EPI_PART><<<dim3(8,8,8), blk, 0, stream>>>(h2,4096,0, gV,4096,0, nullptr,uV, part,1024,1048576, nullptr, 1024, 4);
        reduce_k<<<1024, blk, 0, stream>>>(part,                1048576, 4, gr);
        reduce_k<<<1024, blk, 0, stream>>>(part + 4L*1048576,   1048576, 4, ur);
    } else {
        gemm_bt<EPI_BF16><<<dim3(8,8,1), blk, 0, stream>>>(h2,4096,0, gV,4096,0, nullptr,nullptr, gr,1024,0, nullptr, 4096, 1);
        gemm_bt<EPI_BF16><<<dim3(8,8,1), blk, 0, stream>>>(h2,4096,0, uV,4096,0, nullptr,nullptr, ur,1024,0, nullptr, 4096, 1);
    }
    gemm_bt<EPI_SILU><<<dim3(8,112,1), blk, 0, stream>>>(gr,1024,0, gUs,1024,0, ur, uUs, hmid,14336,0, nullptr, 1024, 1);
    if (big) {
        // hmid @ dV^T: K=14336 split 7 -> 448 blocks
        gemm_bt<EPI_PART><<<dim3(8,8,7), blk, 0, stream>>>(hmid,14336,0, dV,14336,0, nullptr,nullptr, part,1024,1048576, nullptr, 2048, 7);
        reduce_k<<<1024, blk, 0, stream>>>(part, 1048576, 7, dr);
    } else {
        gemm_bt<EPI_BF16><<<dim3(8,8,1), blk, 0, stream>>>(hmid,14336,0, dV,14336,0, nullptr,nullptr, dr,1024,0, nullptr, 14336, 1);
    }
    gemm_bt<EPI_F32ADD><<<dim3(8,32,1), blk, 0, stream>>>(dr,1024,0, dUs,1024,0, nullptr,nullptr, OUT,4096,0, OUT, 1024, 1);
}

// Round 4
// 699.443 us; speedup vs baseline: 2.8008x; 1.1759x over previous
//
#include <hip/hip_runtime.h>
#include <math.h>

// ---------------------------------------------------------------------------
// FlashSVD LLaMA block, round 4: round-3 structure with two fixes:
//  (1) A-staging chunk math corrected for BK=64 (ci>>3 / ci&7) — r3's NaN bug.
//  (2) bijective XOR chunk-swizzle (chunk ^= row&7): pre-swizzled GLOBAL
//      source for A (LDS linear, required by global_load_lds), both-sides
//      swizzle for reg-staged B, matching XOR on fragment ds_reads.
// ---------------------------------------------------------------------------

typedef __bf16 bf16;
typedef __bf16 bf16x8 __attribute__((ext_vector_type(8)));
typedef __bf16 bf16x4 __attribute__((ext_vector_type(4)));
typedef float  f32x4  __attribute__((ext_vector_type(4)));

#define EPI_BF16   0
#define EPI_BF16T  1   // transposed bf16 store (V in [d][t] layout)
#define EPI_F32ADD 2   // fp32 store with residual add
#define EPI_SILU1  3   // store silu(acc) bf16
#define EPI_MUL    4   // RMW: C *= acc (bf16)
#define EPI_PART   5   // fp32 partial plane store (split-K)

__device__ __forceinline__ void gld16(const void* g, void* l) {
    __builtin_amdgcn_global_load_lds(
        (const __attribute__((address_space(1))) unsigned int*)g,
        (__attribute__((address_space(3))) unsigned int*)l, 16, 0, 0);
}

// ---------------------------------------------------------------------------
// 128x128 tile, BK=64, 4 waves (2x2 of 64x64), LDS 2x(16KB A + 16KB B).
// A bf16 [M,K] via global_load_lds (source pre-swizzled); B fp32 [N,K] via
// regs (fp32->bf16, swizzled ds_write). grid.z = batch*nsplit; zb selects B2
// when given (two GEMMs sharing A).
// ---------------------------------------------------------------------------
template<int EPI>
__global__ __launch_bounds__(256)
void gemm2(const bf16* __restrict__ A, int lda, long sA,
           const float* __restrict__ B, int ldb, long sB, const float* __restrict__ B2,
           void* __restrict__ Cv, int ldc, long sC,
           const float* __restrict__ R, int Kc, int nsplit)
{
    __shared__ __align__(16) bf16 As[2][128 * 64];
    __shared__ __align__(16) bf16 Bs[2][128 * 64];

    const int tid = threadIdx.x, lane = tid & 63, w = tid >> 6;
    const int wr = w >> 1, wc = w & 1;
    const int bm = blockIdx.x, bn = blockIdx.y, bz = blockIdx.z;
    const int ks = bz % nsplit, zb = bz / nsplit;

    const float* Bp = (B2 != nullptr && zb != 0) ? B2 : B;
    const bf16*  Ab = A  + (long)zb * sA + (long)(bm * 128) * lda + (long)ks * Kc;
    const float* Bb = Bp + (long)zb * sB + (long)(bn * 128) * ldb + (long)ks * Kc;

    const int g = lane >> 4, r = lane & 15;
    f32x4 acc[4][4] = {};

    // A: 1024 16B-chunks/tile. LDS slot ci (linear) holds global
    // (row=ci>>3, chunk (ci&7)^(row&7)) -- source pre-swizzle, XOR on read.
    // B: 2048 float4/tile; p=i*256+tid: row=p>>4, c4=p&15; ds_write swizzled.
    const int nt = Kc >> 6;
    int cur = 0;

    { // prologue: stage tile 0
        #pragma unroll
        for (int i = 0; i < 4; i++) {
            int cb = i * 256 + w * 64, ci = cb + lane;
            int arow = ci >> 3, acol = ((ci & 7) ^ (arow & 7)) * 8;
            gld16(Ab + (long)arow * lda + acol, &As[0][cb * 8]);
        }
        float4 fb[8];
        #pragma unroll
        for (int i = 0; i < 8; i++) {
            int p = i * 256 + tid;
            fb[i] = *(const float4*)(Bb + (long)(p >> 4) * ldb + (p & 15) * 4);
        }
        #pragma unroll
        for (int i = 0; i < 8; i++) {
            int p = i * 256 + tid, brow = p >> 4, c4 = p & 15;
            bf16x4 h = {(bf16)fb[i].x, (bf16)fb[i].y, (bf16)fb[i].z, (bf16)fb[i].w};
            *(bf16x4*)&Bs[0][brow * 64 + (((c4 >> 1) ^ (brow & 7)) * 8) + (c4 & 1) * 4] = h;
        }
    }
    __syncthreads();

    for (int t = 0; t < nt; t++) {
        float4 fb[8];
        if (t + 1 < nt) { // issue next-tile loads BEFORE compute
            const bf16* An = Ab + (t + 1) * 64;
            #pragma unroll
            for (int i = 0; i < 4; i++) {
                int cb = i * 256 + w * 64, ci = cb + lane;
                int arow = ci >> 3, acol = ((ci & 7) ^ (arow & 7)) * 8;
                gld16(An + (long)arow * lda + acol, &As[cur ^ 1][cb * 8]);
            }
            const float* Bn = Bb + (t + 1) * 64;
            #pragma unroll
            for (int i = 0; i < 8; i++) {
                int p = i * 256 + tid;
                fb[i] = *(const float4*)(Bn + (long)(p >> 4) * ldb + (p & 15) * 4);
            }
        }
        #pragma unroll
        for (int kk = 0; kk < 2; kk++) {
            bf16x8 af[4], bfr[4];
            #pragma unroll
            for (int m = 0; m < 4; m++) {
                int row = wr * 64 + m * 16 + r;
                af[m] = *(const bf16x8*)&As[cur][row * 64 + (((kk * 4 + g) ^ (row & 7)) * 8)];
            }
            #pragma unroll
            for (int n = 0; n < 4; n++) {
                int row = wc * 64 + n * 16 + r;
                bfr[n] = *(const bf16x8*)&Bs[cur][row * 64 + (((kk * 4 + g) ^ (row & 7)) * 8)];
            }
            #pragma unroll
            for (int m = 0; m < 4; m++)
                #pragma unroll
                for (int n = 0; n < 4; n++)
                    acc[m][n] = __builtin_amdgcn_mfma_f32_16x16x32_bf16(af[m], bfr[n], acc[m][n], 0, 0, 0);
        }
        if (t + 1 < nt) { // write-late: B convert lands after compute
            #pragma unroll
            for (int i = 0; i < 8; i++) {
                int p = i * 256 + tid, brow = p >> 4, c4 = p & 15;
                bf16x4 h = {(bf16)fb[i].x, (bf16)fb[i].y, (bf16)fb[i].z, (bf16)fb[i].w};
                *(bf16x4*)&Bs[cur ^ 1][brow * 64 + (((c4 >> 1) ^ (brow & 7)) * 8) + (c4 & 1) * 4] = h;
            }
            __syncthreads();   // drains vmcnt (A lds-loads) + lgkm, one barrier/step
            cur ^= 1;
        }
    }

    // epilogue: C layout col = lane&15, row = (lane>>4)*4 + j
    #pragma unroll
    for (int m = 0; m < 4; m++) {
        #pragma unroll
        for (int n = 0; n < 4; n++) {
            const int row0 = bm * 128 + wr * 64 + m * 16 + g * 4;
            const int col  = bn * 128 + wc * 64 + n * 16 + r;
            #pragma unroll
            for (int j = 0; j < 4; j++) {
                float v = acc[m][n][j];
                long row = row0 + j;
                if constexpr (EPI == EPI_BF16) {
                    ((bf16*)Cv)[(long)zb * sC + row * (long)ldc + col] = (bf16)v;
                } else if constexpr (EPI == EPI_BF16T) {
                    ((bf16*)Cv)[(long)zb * sC + (long)col * ldc + row] = (bf16)v;
                } else if constexpr (EPI == EPI_F32ADD) {
                    long idx = row * (long)ldc + col;
                    ((float*)Cv)[idx] = v + R[idx];
                } else if constexpr (EPI == EPI_PART) {
                    ((float*)Cv)[(long)bz * sC + row * (long)ldc + col] = v;
                } else if constexpr (EPI == EPI_SILU1) {
                    ((bf16*)Cv)[row * (long)ldc + col] = (bf16)(v / (1.f + __expf(-v)));
                } else { // EPI_MUL
                    bf16* p = &((bf16*)Cv)[row * (long)ldc + col];
                    *p = (bf16)((float)*p * v);
                }
            }
        }
    }
}

// ---------------------------------------------------------------------------
__global__ __launch_bounds__(256)
void reduce_k(const float* __restrict__ part, long pe, int np, bf16* __restrict__ out)
{
    long i = ((long)blockIdx.x * 256 + threadIdx.x) * 4;
    float4 s = *(const float4*)&part[i];
    for (int p = 1; p < np; p++) {
        float4 v = *(const float4*)&part[(long)p * pe + i];
        s.x += v.x; s.y += v.y; s.z += v.z; s.w += v.w;
    }
    bf16x4 o = {(bf16)s.x, (bf16)s.y, (bf16)s.z, (bf16)s.w};
    *(bf16x4*)&out[i] = o;
}

__global__ __launch_bounds__(256)
void rmsnorm_k(const float* __restrict__ x, const float* __restrict__ w,
               bf16* __restrict__ out)
{
    const int D = 4096;
    const long row = blockIdx.x;
    const float* xr = x + row * D;
    float4 v[4];
    float ss = 0.f;
    #pragma unroll
    for (int k = 0; k < 4; k++) {
        v[k] = *(const float4*)&xr[threadIdx.x * 4 + k * 1024];
        ss += v[k].x * v[k].x + v[k].y * v[k].y + v[k].z * v[k].z + v[k].w * v[k].w;
    }
    #pragma unroll
    for (int o = 32; o > 0; o >>= 1) ss += __shfl_down(ss, o);
    __shared__ float red[4];
    if ((threadIdx.x & 63) == 0) red[threadIdx.x >> 6] = ss;
    __syncthreads();
    float rs = rsqrtf((red[0] + red[1] + red[2] + red[3]) / D + 1e-5f);
    #pragma unroll
    for (int k = 0; k < 4; k++) {
        int i = threadIdx.x * 4 + k * 1024;
        float4 wv = *(const float4*)&w[i];
        bf16x4 o4 = {(bf16)(v[k].x * rs * wv.x), (bf16)(v[k].y * rs * wv.y),
                     (bf16)(v[k].z * rs * wv.z), (bf16)(v[k].w * rs * wv.w)};
        *(bf16x4*)&out[row * D + i] = o4;
    }
}

__global__ __launch_bounds__(256)
void rope_table_k(float* cs, float* sn)
{
    int idx = blockIdx.x * blockDim.x + threadIdx.x;  // 1024*64
    int t = idx >> 6, i = idx & 63;
    float inv = powf(10000.0f, -(2.0f * i) / 128.0f);
    float a = (float)t * inv;
    cs[idx] = cosf(a);
    sn[idx] = sinf(a);
}

__global__ __launch_bounds__(256)
void rope_k(bf16* qk, const float* __restrict__ cs, const float* __restrict__ sn)
{
    long idx = (long)blockIdx.x * blockDim.x + threadIdx.x;
    int d = idx & 63;
    long ht = idx >> 6;
    int t = (int)(ht & 1023);
    bf16* p = qk + ht * 128;
    float x1 = (float)p[d], x2 = (float)p[d + 64];
    int i1 = d >> 1;
    float c1 = cs[t * 64 + i1],      s1 = sn[t * 64 + i1];
    float c2 = cs[t * 64 + 32 + i1], s2 = sn[t * 64 + 32 + i1];
    p[d]      = (bf16)(x1 * c1 - x2 * s1);
    p[d + 64] = (bf16)(x2 * c2 + x1 * s2);
}

// ---------------------------------------------------------------------------
// Flash attention (causal, GQA 4:1), 4 waves x 16 q-rows, KV tile 64.
// ---------------------------------------------------------------------------
__global__ __launch_bounds__(256)
void attn_k(const bf16* __restrict__ Q,   // [32][1024][128]
            const bf16* __restrict__ Kb,  // [8][1024][128]
            const bf16* __restrict__ Vt,  // [8][128][1024]
            bf16* __restrict__ O)         // [1024][4096]
{
    const int T = 1024;
    __shared__ __align__(16) bf16 Ks[64][128];
    __shared__ __align__(16) bf16 Vs[128][64];
    __shared__ __align__(16) bf16 Ps[4][16][72];

    const int qt = blockIdx.x, h = blockIdx.y, hk = h >> 2;
    const int tid = threadIdx.x, lane = tid & 63, w = tid >> 6;
    const int g = lane >> 4, r = lane & 15;
    const int qrow0 = qt * 64 + w * 16;

    bf16x8 qf[4];
    const bf16* qp = Q + ((long)h * T + qrow0 + r) * 128;
    #pragma unroll
    for (int dc = 0; dc < 4; dc++) qf[dc] = *(const bf16x8*)(qp + dc * 32 + g * 8);

    f32x4 o_acc[8] = {};
    float m_run[4], l_run[4];
    #pragma unroll
    for (int j = 0; j < 4; j++) { m_run[j] = -1e30f; l_run[j] = 0.f; }

    const float scale = 0.08838834764831845f;
    const int kv_end = qt * 64 + 64;

    for (int kv0 = 0; kv0 < kv_end; kv0 += 64) {
        __syncthreads();
        {
            int tr = tid >> 2;
            const bf16* src = Kb + ((long)hk * T + kv0 + tr) * 128;
            #pragma unroll
            for (int q4 = 0; q4 < 4; q4++) {
                int c = (tid & 3) * 4 + q4;
                bf16x8 v = *(const bf16x8*)(src + c * 8);
                *(bf16x8*)&Ks[tr][(c ^ (tr & 7)) * 8] = v;
            }
        }
        {
            int dd = tid >> 1;
            const bf16* src = Vt + ((long)hk * 128 + dd) * T + kv0;
            #pragma unroll
            for (int q4 = 0; q4 < 4; q4++) {
                int c = (tid & 1) * 4 + q4;
                bf16x8 v = *(const bf16x8*)(src + c * 8);
                *(bf16x8*)&Vs[dd][(c ^ (dd & 7)) * 8] = v;
            }
        }
        __syncthreads();

        f32x4 s[4] = {};
        #pragma unroll
        for (int n = 0; n < 4; n++) {
            int tr = n * 16 + r;
            #pragma unroll
            for (int dc = 0; dc < 4; dc++) {
                int c = (dc * 4 + g) ^ (tr & 7);
                bf16x8 kf = *(const bf16x8*)&Ks[tr][c * 8];
                s[n] = __builtin_amdgcn_mfma_f32_16x16x32_bf16(qf[dc], kf, s[n], 0, 0, 0);
            }
        }

        #pragma unroll
        for (int j = 0; j < 4; j++) {
            int qpos = qrow0 + g * 4 + j;
            float mx = m_run[j];
            #pragma unroll
            for (int n = 0; n < 4; n++) {
                int kpos = kv0 + n * 16 + r;
                float sv = s[n][j] * scale;
                sv = (kpos <= qpos) ? sv : -1e30f;
                s[n][j] = sv;
                mx = fmaxf(mx, sv);
            }
            #pragma unroll
            for (int mask = 1; mask < 16; mask <<= 1) mx = fmaxf(mx, __shfl_xor(mx, mask));
            float corr = __expf(m_run[j] - mx);
            l_run[j] *= corr;
            #pragma unroll
            for (int db = 0; db < 8; db++) o_acc[db][j] *= corr;
            float ls = 0.f;
            #pragma unroll
            for (int n = 0; n < 4; n++) {
                float p = __expf(s[n][j] - mx);
                s[n][j] = p;
                ls += p;
            }
            #pragma unroll
            for (int mask = 1; mask < 16; mask <<= 1) ls += __shfl_xor(ls, mask);
            l_run[j] += ls;
            m_run[j] = mx;
        }

        #pragma unroll
        for (int n = 0; n < 4; n++)
            #pragma unroll
            for (int j = 0; j < 4; j++)
                Ps[w][g * 4 + j][n * 16 + r] = (bf16)s[n][j];
        __syncthreads();

        bf16x8 pf[2];
        #pragma unroll
        for (int kc = 0; kc < 2; kc++)
            pf[kc] = *(const bf16x8*)&Ps[w][r][kc * 32 + g * 8];
        #pragma unroll
        for (int db = 0; db < 8; db++) {
            #pragma unroll
            for (int kc = 0; kc < 2; kc++) {
                int dd = db * 16 + r;
                int c = (kc * 4 + g) ^ (dd & 7);
                bf16x8 vf = *(const bf16x8*)&Vs[dd][c * 8];
                o_acc[db] = __builtin_amdgcn_mfma_f32_16x16x32_bf16(pf[kc], vf, o_acc[db], 0, 0, 0);
            }
        }
    }

    #pragma unroll
    for (int db = 0; db < 8; db++) {
        #pragma unroll
        for (int j = 0; j < 4; j++) {
            int t = qrow0 + g * 4 + j;
            float v = o_acc[db][j] / l_run[j];
            O[(long)t * 4096 + h * 128 + db * 16 + r] = (bf16)v;
        }
    }
}

// ---------------------------------------------------------------------------
extern "C" void kernel_launch(void* const* d_in, const int* in_sizes, int n_in,
                              void* d_out, int out_size, void* d_ws, size_t ws_size,
                              hipStream_t stream)
{
    const float* X   = (const float*)d_in[0];
    const float* LN1 = (const float*)d_in[1];
    const float* LN2 = (const float*)d_in[2];
    const float* qUs = (const float*)d_in[3];
    const float* qV  = (const float*)d_in[4];
    const float* kUs = (const float*)d_in[5];
    const float* kV  = (const float*)d_in[6];
    const float* vUs = (const float*)d_in[7];
    const float* vV  = (const float*)d_in[8];
    const float* oUs = (const float*)d_in[9];
    const float* oV  = (const float*)d_in[10];
    const float* gUs = (const float*)d_in[11];
    const float* gV  = (const float*)d_in[12];
    const float* uUs = (const float*)d_in[13];
    const float* uV  = (const float*)d_in[14];
    const float* dUs = (const float*)d_in[15];
    const float* dV  = (const float*)d_in[16];
    float* OUT = (float*)d_out;

    char* w = (char*)d_ws;
    bf16*  h1   = (bf16*)(w + 0);          // [1024,4096]
    bf16*  xrq  = (bf16*)(w + 8388608);    // [1024,2048]
    bf16*  xrk  = (bf16*)(w + 12582912);   // [1024,512]
    bf16*  xrv  = (bf16*)(w + 13631488);   // [1024,512]
    bf16*  qb   = (bf16*)(w + 14680064);   // [32,1024,128]
    bf16*  kb   = (bf16*)(w + 23068672);   // [8,1024,128]
    bf16*  vt   = (bf16*)(w + 25165824);   // [8,128,1024]
    float* cs   = (float*)(w + 27262976);  // [1024,64]
    float* sn   = (float*)(w + 27525120);  // [1024,64]
    bf16*  att  = (bf16*)(w + 27787264);   // [1024,4096]
    bf16*  r1   = (bf16*)(w + 36175872);   // [1024,1024]
    // MLP phase aliases (attn intermediates dead by then)
    bf16*  h2   = (bf16*)(w + 0);          // [1024,4096]
    bf16*  gr   = (bf16*)(w + 8388608);    // [1024,1024]
    bf16*  ur   = (bf16*)(w + 10485760);   // [1024,1024]
    bf16*  hmid = (bf16*)(w + 12582912);   // [1024,14336]
    bf16*  dr   = (bf16*)(w + 41943040);   // [1024,1024]
    const size_t ARENA = 44040192;
    float* part = (float*)(w + ARENA);
    const bool med = ws_size >= (size_t)(ARENA + 33554432);

    dim3 blk(256);

    rmsnorm_k<<<1024, blk, 0, stream>>>(X, LN1, h1);

    if (med) {
        // xr_q: K=4096 split 4 -> 512 blocks
        gemm2<EPI_PART><<<dim3(8,16,4), blk, 0, stream>>>(h1,4096,0, qV,4096,0,nullptr, part,2048,2097152, nullptr, 1024, 4);
        reduce_k<<<2048, blk, 0, stream>>>(part, 2097152, 4, xrq);
        // xr_k + xr_v batched (share A=h1), split 4 -> 256 blocks
        gemm2<EPI_PART><<<dim3(8,4,8), blk, 0, stream>>>(h1,4096,0, kV,4096,0,vV, part,512,524288, nullptr, 1024, 4);
        reduce_k<<<512, blk, 0, stream>>>(part,             524288, 4, xrk);
        reduce_k<<<512, blk, 0, stream>>>(part + 4L*524288, 524288, 4, xrv);
    } else {
        gemm2<EPI_BF16><<<dim3(8,16,1), blk, 0, stream>>>(h1,4096,0, qV,4096,0,nullptr, xrq,2048,0, nullptr, 4096, 1);
        gemm2<EPI_BF16><<<dim3(8, 4,1), blk, 0, stream>>>(h1,4096,0, kV,4096,0,nullptr, xrk, 512,0, nullptr, 4096, 1);
        gemm2<EPI_BF16><<<dim3(8, 4,1), blk, 0, stream>>>(h1,4096,0, vV,4096,0,nullptr, xrv, 512,0, nullptr, 4096, 1);
    }

    gemm2<EPI_BF16 ><<<dim3(8,1,32), blk, 0, stream>>>(xrq,2048,64, qUs,64,8192,nullptr, qb,128,131072, nullptr, 64, 1);
    gemm2<EPI_BF16 ><<<dim3(8,1, 8), blk, 0, stream>>>(xrk, 512,64, kUs,64,8192,nullptr, kb,128,131072, nullptr, 64, 1);
    gemm2<EPI_BF16T><<<dim3(8,1, 8), blk, 0, stream>>>(xrv, 512,64, vUs,64,8192,nullptr, vt,1024,131072, nullptr, 64, 1);
    rope_table_k<<<256, blk, 0, stream>>>(cs, sn);
    rope_k<<<8192, blk, 0, stream>>>(qb, cs, sn);
    rope_k<<<2048, blk, 0, stream>>>(kb, cs, sn);
    attn_k<<<dim3(16,32), blk, 0, stream>>>(qb, kb, vt, att);

    if (med) {
        gemm2<EPI_PART><<<dim3(8,8,4), blk, 0, stream>>>(att,4096,0, oV,4096,0,nullptr, part,1024,1048576, nullptr, 1024, 4);
        reduce_k<<<1024, blk, 0, stream>>>(part, 1048576, 4, r1);
    } else {
        gemm2<EPI_BF16><<<dim3(8,8,1), blk, 0, stream>>>(att,4096,0, oV,4096,0,nullptr, r1,1024,0, nullptr, 4096, 1);
    }
    gemm2<EPI_F32ADD><<<dim3(8,32,1), blk, 0, stream>>>(r1,1024,0, oUs,1024,0,nullptr, OUT,4096,0, X, 1024, 1);

    // --- MLP half ---
    rmsnorm_k<<<1024, blk, 0, stream>>>(OUT, LN2, h2);
    if (med) {
        gemm2<EPI_PART><<<dim3(8,8,8), blk, 0, stream>>>(h2,4096,0, gV,4096,0,uV, part,1024,1048576, nullptr, 1024, 4);
        reduce_k<<<1024, blk, 0, stream>>>(part,              1048576, 4, gr);
        reduce_k<<<1024, blk, 0, stream>>>(part + 4L*1048576, 1048576, 4, ur);
    } else {
        gemm2<EPI_BF16><<<dim3(8,8,1), blk, 0, stream>>>(h2,4096,0, gV,4096,0,nullptr, gr,1024,0, nullptr, 4096, 1);
        gemm2<EPI_BF16><<<dim3(8,8,1), blk, 0, stream>>>(h2,4096,0, uV,4096,0,nullptr, ur,1024,0, nullptr, 4096, 1);
    }
    gemm2<EPI_SILU1><<<dim3(8,112,1), blk, 0, stream>>>(gr,1024,0, gUs,1024,0,nullptr, hmid,14336,0, nullptr, 1024, 1);
    gemm2<EPI_MUL  ><<<dim3(8,112,1), blk, 0, stream>>>(ur,1024,0, uUs,1024,0,nullptr, hmid,14336,0, nullptr, 1024, 1);
    if (med) {
        gemm2<EPI_PART><<<dim3(8,8,7), blk, 0, stream>>>(hmid,14336,0, dV,14336,0,nullptr, part,1024,1048576, nullptr, 2048, 7);
        reduce_k<<<1024, blk, 0, stream>>>(part, 1048576, 7, dr);
    } else {
        gemm2<EPI_BF16><<<dim3(8,8,1), blk, 0, stream>>>(hmid,14336,0, dV,14336,0,nullptr, dr,1024,0, nullptr, 14336, 1);
    }
    gemm2<EPI_F32ADD><<<dim3(8,32,1), blk, 0, stream>>>(dr,1024,0, dUs,1024,0,nullptr, OUT,4096,0, OUT, 1024, 1);
}

// Round 5
// 570.917 us; speedup vs baseline: 3.4313x; 1.2251x over previous
//
#include <hip/hip_runtime.h>
#include <math.h>

// ---------------------------------------------------------------------------
// FlashSVD LLaMA block, round 5:
//  - all weights pre-converted fp32->bf16 once (batched cvt kernel) so every
//    GEMM stages BOTH operands via global_load_lds width-16 (no VALU convert)
//  - gemm3: m97-structure 128x128/BK=64, single-buffered 32KB LDS (5 blk/CU),
//    2-barrier K-step, pre-swizzled global source (conflict-free ds_read)
//  - bijective XCD swizzle (bm-fast chunks per XCD) for B-panel L2 locality
//  - round-4 gemm2 kept as workspace-size fallback
// ---------------------------------------------------------------------------

typedef __bf16 bf16;
typedef __bf16 bf16x8 __attribute__((ext_vector_type(8)));
typedef __bf16 bf16x4 __attribute__((ext_vector_type(4)));
typedef float  f32x4  __attribute__((ext_vector_type(4)));

#define EPI_BF16   0
#define EPI_BF16T  1   // transposed bf16 store (V in [d][t] layout)
#define EPI_F32ADD 2   // fp32 store with residual add
#define EPI_SILU1  3   // store silu(acc) bf16
#define EPI_MUL    4   // RMW: C *= acc (bf16)
#define EPI_PART   5   // fp32 partial plane store (split-K)

__device__ __forceinline__ void gld16(const void* g, void* l) {
    __builtin_amdgcn_global_load_lds(
        (const __attribute__((address_space(1))) unsigned int*)g,
        (__attribute__((address_space(3))) unsigned int*)l, 16, 0, 0);
}

// ---------------------------------------------------------------------------
// gemm3: pure-bf16, 128x128 tile, BK=64, 4 waves (2x2 of 64x64), 32KB LDS
// single-buffered, 2 barriers per K-step. Both operands via global_load_lds
// with pre-swizzled global source (chunk ^= row&7), XOR on fragment reads.
// Grid: dim3(nwg,1,z); logical id = XCD-bijective remap; bm=id%gx, bn=id/gx.
// ---------------------------------------------------------------------------
template<int EPI>
__global__ __launch_bounds__(256)
void gemm3(const bf16* __restrict__ A, int lda, long sA,
           const bf16* __restrict__ B, int ldb, long sB, const bf16* __restrict__ B2,
           void* __restrict__ Cv, int ldc, long sC,
           const float* __restrict__ R, int Kc, int nsplit, int gx)
{
    __shared__ __align__(16) bf16 As[128 * 64];
    __shared__ __align__(16) bf16 Bs[128 * 64];

    const int tid = threadIdx.x, lane = tid & 63, w = tid >> 6;
    const int wr = w >> 1, wc = w & 1;

    int id = blockIdx.x;
    {   // bijective XCD remap (m204): XCD x owns a contiguous chunk of ids
        const int nwg = gridDim.x;
        int q = nwg >> 3, rr = nwg & 7;
        int xcd = id & 7, off = id >> 3;
        id = (xcd < rr ? xcd * (q + 1) : rr * (q + 1) + (xcd - rr) * q) + off;
    }
    const int bm = id % gx, bn = id / gx, bz = blockIdx.z;
    const int ks = bz % nsplit, zb = bz / nsplit;

    const bf16* Bp = (B2 != nullptr && zb != 0) ? B2 : B;
    const bf16* Ab = A  + (long)zb * sA + (long)(bm * 128) * lda + (long)ks * Kc;
    const bf16* Bb = Bp + (long)zb * sB + (long)(bn * 128) * ldb + (long)ks * Kc;

    const int g = lane >> 4, r = lane & 15;
    f32x4 acc[4][4] = {};
    const int nt = Kc >> 6;

    for (int t = 0; t < nt; t++) {
        if (t) __syncthreads();              // compute(t-1) done in all waves
        const bf16* At = Ab + t * 64;
        const bf16* Bt = Bb + t * 64;
        #pragma unroll
        for (int i = 0; i < 4; i++) {        // 1024 chunks each for A and B
            int cb = w * 256 + i * 64, ci = cb + lane;
            int row = ci >> 3, col = ((ci & 7) ^ (row & 7)) * 8;
            gld16(At + (long)row * lda + col, &As[cb * 8]);
            gld16(Bt + (long)row * ldb + col, &Bs[cb * 8]);
        }
        __syncthreads();                     // drains vmcnt -> tile resident
        #pragma unroll
        for (int kk = 0; kk < 2; kk++) {
            bf16x8 af[4], bfr[4];
            #pragma unroll
            for (int m = 0; m < 4; m++) {
                int row = wr * 64 + m * 16 + r;
                af[m] = *(const bf16x8*)&As[row * 64 + (((kk * 4 + g) ^ (row & 7)) * 8)];
            }
            #pragma unroll
            for (int n = 0; n < 4; n++) {
                int row = wc * 64 + n * 16 + r;
                bfr[n] = *(const bf16x8*)&Bs[row * 64 + (((kk * 4 + g) ^ (row & 7)) * 8)];
            }
            #pragma unroll
            for (int m = 0; m < 4; m++)
                #pragma unroll
                for (int n = 0; n < 4; n++)
                    acc[m][n] = __builtin_amdgcn_mfma_f32_16x16x32_bf16(af[m], bfr[n], acc[m][n], 0, 0, 0);
        }
    }

    // epilogue: C layout col = lane&15, row = (lane>>4)*4 + j
    #pragma unroll
    for (int m = 0; m < 4; m++) {
        #pragma unroll
        for (int n = 0; n < 4; n++) {
            const int row0 = bm * 128 + wr * 64 + m * 16 + g * 4;
            const int col  = bn * 128 + wc * 64 + n * 16 + r;
            #pragma unroll
            for (int j = 0; j < 4; j++) {
                float v = acc[m][n][j];
                long row = row0 + j;
                if constexpr (EPI == EPI_BF16) {
                    ((bf16*)Cv)[(long)zb * sC + row * (long)ldc + col] = (bf16)v;
                } else if constexpr (EPI == EPI_BF16T) {
                    ((bf16*)Cv)[(long)zb * sC + (long)col * ldc + row] = (bf16)v;
                } else if constexpr (EPI == EPI_F32ADD) {
                    long idx = row * (long)ldc + col;
                    ((float*)Cv)[idx] = v + R[idx];
                } else if constexpr (EPI == EPI_PART) {
                    ((float*)Cv)[(long)bz * sC + row * (long)ldc + col] = v;
                } else if constexpr (EPI == EPI_SILU1) {
                    ((bf16*)Cv)[row * (long)ldc + col] = (bf16)(v / (1.f + __expf(-v)));
                } else { // EPI_MUL
                    bf16* p = &((bf16*)Cv)[row * (long)ldc + col];
                    *p = (bf16)((float)*p * v);
                }
            }
        }
    }
}

// ---------------------------------------------------------------------------
// gemm2 (round-4 fallback): fp32 B with in-kernel convert, BK=64 dbuf.
// ---------------------------------------------------------------------------
template<int EPI>
__global__ __launch_bounds__(256)
void gemm2(const bf16* __restrict__ A, int lda, long sA,
           const float* __restrict__ B, int ldb, long sB, const float* __restrict__ B2,
           void* __restrict__ Cv, int ldc, long sC,
           const float* __restrict__ R, int Kc, int nsplit)
{
    __shared__ __align__(16) bf16 As[2][128 * 64];
    __shared__ __align__(16) bf16 Bs[2][128 * 64];

    const int tid = threadIdx.x, lane = tid & 63, w = tid >> 6;
    const int wr = w >> 1, wc = w & 1;
    const int bm = blockIdx.x, bn = blockIdx.y, bz = blockIdx.z;
    const int ks = bz % nsplit, zb = bz / nsplit;

    const float* Bp = (B2 != nullptr && zb != 0) ? B2 : B;
    const bf16*  Ab = A  + (long)zb * sA + (long)(bm * 128) * lda + (long)ks * Kc;
    const float* Bb = Bp + (long)zb * sB + (long)(bn * 128) * ldb + (long)ks * Kc;

    const int g = lane >> 4, r = lane & 15;
    f32x4 acc[4][4] = {};
    const int nt = Kc >> 6;
    int cur = 0;

    {
        #pragma unroll
        for (int i = 0; i < 4; i++) {
            int cb = i * 256 + w * 64, ci = cb + lane;
            int arow = ci >> 3, acol = ((ci & 7) ^ (arow & 7)) * 8;
            gld16(Ab + (long)arow * lda + acol, &As[0][cb * 8]);
        }
        float4 fb[8];
        #pragma unroll
        for (int i = 0; i < 8; i++) {
            int p = i * 256 + tid;
            fb[i] = *(const float4*)(Bb + (long)(p >> 4) * ldb + (p & 15) * 4);
        }
        #pragma unroll
        for (int i = 0; i < 8; i++) {
            int p = i * 256 + tid, brow = p >> 4, c4 = p & 15;
            bf16x4 h = {(bf16)fb[i].x, (bf16)fb[i].y, (bf16)fb[i].z, (bf16)fb[i].w};
            *(bf16x4*)&Bs[0][brow * 64 + (((c4 >> 1) ^ (brow & 7)) * 8) + (c4 & 1) * 4] = h;
        }
    }
    __syncthreads();

    for (int t = 0; t < nt; t++) {
        float4 fb[8];
        if (t + 1 < nt) {
            const bf16* An = Ab + (t + 1) * 64;
            #pragma unroll
            for (int i = 0; i < 4; i++) {
                int cb = i * 256 + w * 64, ci = cb + lane;
                int arow = ci >> 3, acol = ((ci & 7) ^ (arow & 7)) * 8;
                gld16(An + (long)arow * lda + acol, &As[cur ^ 1][cb * 8]);
            }
            const float* Bn = Bb + (t + 1) * 64;
            #pragma unroll
            for (int i = 0; i < 8; i++) {
                int p = i * 256 + tid;
                fb[i] = *(const float4*)(Bn + (long)(p >> 4) * ldb + (p & 15) * 4);
            }
        }
        #pragma unroll
        for (int kk = 0; kk < 2; kk++) {
            bf16x8 af[4], bfr[4];
            #pragma unroll
            for (int m = 0; m < 4; m++) {
                int row = wr * 64 + m * 16 + r;
                af[m] = *(const bf16x8*)&As[cur][row * 64 + (((kk * 4 + g) ^ (row & 7)) * 8)];
            }
            #pragma unroll
            for (int n = 0; n < 4; n++) {
                int row = wc * 64 + n * 16 + r;
                bfr[n] = *(const bf16x8*)&Bs[cur][row * 64 + (((kk * 4 + g) ^ (row & 7)) * 8)];
            }
            #pragma unroll
            for (int m = 0; m < 4; m++)
                #pragma unroll
                for (int n = 0; n < 4; n++)
                    acc[m][n] = __builtin_amdgcn_mfma_f32_16x16x32_bf16(af[m], bfr[n], acc[m][n], 0, 0, 0);
        }
        if (t + 1 < nt) {
            #pragma unroll
            for (int i = 0; i < 8; i++) {
                int p = i * 256 + tid, brow = p >> 4, c4 = p & 15;
                bf16x4 h = {(bf16)fb[i].x, (bf16)fb[i].y, (bf16)fb[i].z, (bf16)fb[i].w};
                *(bf16x4*)&Bs[cur ^ 1][brow * 64 + (((c4 >> 1) ^ (brow & 7)) * 8) + (c4 & 1) * 4] = h;
            }
            __syncthreads();
            cur ^= 1;
        }
    }

    #pragma unroll
    for (int m = 0; m < 4; m++) {
        #pragma unroll
        for (int n = 0; n < 4; n++) {
            const int row0 = bm * 128 + wr * 64 + m * 16 + g * 4;
            const int col  = bn * 128 + wc * 64 + n * 16 + r;
            #pragma unroll
            for (int j = 0; j < 4; j++) {
                float v = acc[m][n][j];
                long row = row0 + j;
                if constexpr (EPI == EPI_BF16) {
                    ((bf16*)Cv)[(long)zb * sC + row * (long)ldc + col] = (bf16)v;
                } else if constexpr (EPI == EPI_BF16T) {
                    ((bf16*)Cv)[(long)zb * sC + (long)col * ldc + row] = (bf16)v;
                } else if constexpr (EPI == EPI_F32ADD) {
                    long idx = row * (long)ldc + col;
                    ((float*)Cv)[idx] = v + R[idx];
                } else if constexpr (EPI == EPI_PART) {
                    ((float*)Cv)[(long)bz * sC + row * (long)ldc + col] = v;
                } else if constexpr (EPI == EPI_SILU1) {
                    ((bf16*)Cv)[row * (long)ldc + col] = (bf16)(v / (1.f + __expf(-v)));
                } else {
                    bf16* p = &((bf16*)Cv)[row * (long)ldc + col];
                    *p = (bf16)((float)*p * v);
                }
            }
        }
    }
}

// ---------------------------------------------------------------------------
// Batched fp32 -> bf16 weight conversion (14 tensors, struct-by-value args).
// ---------------------------------------------------------------------------
struct CvtArgs { const float* s[14]; bf16* d[14]; int n[14]; };

__global__ __launch_bounds__(256)
void cvt_k(CvtArgs a)
{
    const long stride = (long)gridDim.x * 256;
    #pragma unroll 1
    for (int ti = 0; ti < 14; ti++) {
        const float* __restrict__ s = a.s[ti];
        bf16* __restrict__ d = a.d[ti];
        long n8 = (long)a.n[ti] >> 3;
        for (long i = (long)blockIdx.x * 256 + threadIdx.x; i < n8; i += stride) {
            const float4* sp = (const float4*)s + i * 2;
            float4 f0 = sp[0], f1 = sp[1];
            bf16x8 h = {(bf16)f0.x,(bf16)f0.y,(bf16)f0.z,(bf16)f0.w,
                        (bf16)f1.x,(bf16)f1.y,(bf16)f1.z,(bf16)f1.w};
            *(bf16x8*)(d + i * 8) = h;
        }
    }
}

// ---------------------------------------------------------------------------
__global__ __launch_bounds__(256)
void reduce_k(const float* __restrict__ part, long pe, int np, bf16* __restrict__ out)
{
    long i = ((long)blockIdx.x * 256 + threadIdx.x) * 4;
    float4 s = *(const float4*)&part[i];
    for (int p = 1; p < np; p++) {
        float4 v = *(const float4*)&part[(long)p * pe + i];
        s.x += v.x; s.y += v.y; s.z += v.z; s.w += v.w;
    }
    bf16x4 o = {(bf16)s.x, (bf16)s.y, (bf16)s.z, (bf16)s.w};
    *(bf16x4*)&out[i] = o;
}

__global__ __launch_bounds__(256)
void rmsnorm_k(const float* __restrict__ x, const float* __restrict__ w,
               bf16* __restrict__ out)
{
    const int D = 4096;
    const long row = blockIdx.x;
    const float* xr = x + row * D;
    float4 v[4];
    float ss = 0.f;
    #pragma unroll
    for (int k = 0; k < 4; k++) {
        v[k] = *(const float4*)&xr[threadIdx.x * 4 + k * 1024];
        ss += v[k].x * v[k].x + v[k].y * v[k].y + v[k].z * v[k].z + v[k].w * v[k].w;
    }
    #pragma unroll
    for (int o = 32; o > 0; o >>= 1) ss += __shfl_down(ss, o);
    __shared__ float red[4];
    if ((threadIdx.x & 63) == 0) red[threadIdx.x >> 6] = ss;
    __syncthreads();
    float rs = rsqrtf((red[0] + red[1] + red[2] + red[3]) / D + 1e-5f);
    #pragma unroll
    for (int k = 0; k < 4; k++) {
        int i = threadIdx.x * 4 + k * 1024;
        float4 wv = *(const float4*)&w[i];
        bf16x4 o4 = {(bf16)(v[k].x * rs * wv.x), (bf16)(v[k].y * rs * wv.y),
                     (bf16)(v[k].z * rs * wv.z), (bf16)(v[k].w * rs * wv.w)};
        *(bf16x4*)&out[row * D + i] = o4;
    }
}

__global__ __launch_bounds__(256)
void rope_table_k(float* cs, float* sn)
{
    int idx = blockIdx.x * blockDim.x + threadIdx.x;  // 1024*64
    int t = idx >> 6, i = idx & 63;
    float inv = powf(10000.0f, -(2.0f * i) / 128.0f);
    float a = (float)t * inv;
    cs[idx] = cosf(a);
    sn[idx] = sinf(a);
}

__global__ __launch_bounds__(256)
void rope_k(bf16* qk, const float* __restrict__ cs, const float* __restrict__ sn)
{
    long idx = (long)blockIdx.x * blockDim.x + threadIdx.x;
    int d = idx & 63;
    long ht = idx >> 6;
    int t = (int)(ht & 1023);
    bf16* p = qk + ht * 128;
    float x1 = (float)p[d], x2 = (float)p[d + 64];
    int i1 = d >> 1;
    float c1 = cs[t * 64 + i1],      s1 = sn[t * 64 + i1];
    float c2 = cs[t * 64 + 32 + i1], s2 = sn[t * 64 + 32 + i1];
    p[d]      = (bf16)(x1 * c1 - x2 * s1);
    p[d + 64] = (bf16)(x2 * c2 + x1 * s2);
}

// ---------------------------------------------------------------------------
// Flash attention (causal, GQA 4:1), 4 waves x 16 q-rows, KV tile 64.
// ---------------------------------------------------------------------------
__global__ __launch_bounds__(256)
void attn_k(const bf16* __restrict__ Q,   // [32][1024][128]
            const bf16* __restrict__ Kb,  // [8][1024][128]
            const bf16* __restrict__ Vt,  // [8][128][1024]
            bf16* __restrict__ O)         // [1024][4096]
{
    const int T = 1024;
    __shared__ __align__(16) bf16 Ks[64][128];
    __shared__ __align__(16) bf16 Vs[128][64];
    __shared__ __align__(16) bf16 Ps[4][16][72];

    const int qt = blockIdx.x, h = blockIdx.y, hk = h >> 2;
    const int tid = threadIdx.x, lane = tid & 63, w = tid >> 6;
    const int g = lane >> 4, r = lane & 15;
    const int qrow0 = qt * 64 + w * 16;

    bf16x8 qf[4];
    const bf16* qp = Q + ((long)h * T + qrow0 + r) * 128;
    #pragma unroll
    for (int dc = 0; dc < 4; dc++) qf[dc] = *(const bf16x8*)(qp + dc * 32 + g * 8);

    f32x4 o_acc[8] = {};
    float m_run[4], l_run[4];
    #pragma unroll
    for (int j = 0; j < 4; j++) { m_run[j] = -1e30f; l_run[j] = 0.f; }

    const float scale = 0.08838834764831845f;
    const int kv_end = qt * 64 + 64;

    for (int kv0 = 0; kv0 < kv_end; kv0 += 64) {
        __syncthreads();
        {
            int tr = tid >> 2;
            const bf16* src = Kb + ((long)hk * T + kv0 + tr) * 128;
            #pragma unroll
            for (int q4 = 0; q4 < 4; q4++) {
                int c = (tid & 3) * 4 + q4;
                bf16x8 v = *(const bf16x8*)(src + c * 8);
                *(bf16x8*)&Ks[tr][(c ^ (tr & 7)) * 8] = v;
            }
        }
        {
            int dd = tid >> 1;
            const bf16* src = Vt + ((long)hk * 128 + dd) * T + kv0;
            #pragma unroll
            for (int q4 = 0; q4 < 4; q4++) {
                int c = (tid & 1) * 4 + q4;
                bf16x8 v = *(const bf16x8*)(src + c * 8);
                *(bf16x8*)&Vs[dd][(c ^ (dd & 7)) * 8] = v;
            }
        }
        __syncthreads();

        f32x4 s[4] = {};
        #pragma unroll
        for (int n = 0; n < 4; n++) {
            int tr = n * 16 + r;
            #pragma unroll
            for (int dc = 0; dc < 4; dc++) {
                int c = (dc * 4 + g) ^ (tr & 7);
                bf16x8 kf = *(const bf16x8*)&Ks[tr][c * 8];
                s[n] = __builtin_amdgcn_mfma_f32_16x16x32_bf16(qf[dc], kf, s[n], 0, 0, 0);
            }
        }

        #pragma unroll
        for (int j = 0; j < 4; j++) {
            int qpos = qrow0 + g * 4 + j;
            float mx = m_run[j];
            #pragma unroll
            for (int n = 0; n < 4; n++) {
                int kpos = kv0 + n * 16 + r;
                float sv = s[n][j] * scale;
                sv = (kpos <= qpos) ? sv : -1e30f;
                s[n][j] = sv;
                mx = fmaxf(mx, sv);
            }
            #pragma unroll
            for (int mask = 1; mask < 16; mask <<= 1) mx = fmaxf(mx, __shfl_xor(mx, mask));
            float corr = __expf(m_run[j] - mx);
            l_run[j] *= corr;
            #pragma unroll
            for (int db = 0; db < 8; db++) o_acc[db][j] *= corr;
            float ls = 0.f;
            #pragma unroll
            for (int n = 0; n < 4; n++) {
                float p = __expf(s[n][j] - mx);
                s[n][j] = p;
                ls += p;
            }
            #pragma unroll
            for (int mask = 1; mask < 16; mask <<= 1) ls += __shfl_xor(ls, mask);
            l_run[j] += ls;
            m_run[j] = mx;
        }

        #pragma unroll
        for (int n = 0; n < 4; n++)
            #pragma unroll
            for (int j = 0; j < 4; j++)
                Ps[w][g * 4 + j][n * 16 + r] = (bf16)s[n][j];
        __syncthreads();

        bf16x8 pf[2];
        #pragma unroll
        for (int kc = 0; kc < 2; kc++)
            pf[kc] = *(const bf16x8*)&Ps[w][r][kc * 32 + g * 8];
        #pragma unroll
        for (int db = 0; db < 8; db++) {
            #pragma unroll
            for (int kc = 0; kc < 2; kc++) {
                int dd = db * 16 + r;
                int c = (kc * 4 + g) ^ (dd & 7);
                bf16x8 vf = *(const bf16x8*)&Vs[dd][c * 8];
                o_acc[db] = __builtin_amdgcn_mfma_f32_16x16x32_bf16(pf[kc], vf, o_acc[db], 0, 0, 0);
            }
        }
    }

    #pragma unroll
    for (int db = 0; db < 8; db++) {
        #pragma unroll
        for (int j = 0; j < 4; j++) {
            int t = qrow0 + g * 4 + j;
            float v = o_acc[db][j] / l_run[j];
            O[(long)t * 4096 + h * 128 + db * 16 + r] = (bf16)v;
        }
    }
}

// ---------------------------------------------------------------------------
extern "C" void kernel_launch(void* const* d_in, const int* in_sizes, int n_in,
                              void* d_out, int out_size, void* d_ws, size_t ws_size,
                              hipStream_t stream)
{
    const float* X   = (const float*)d_in[0];
    const float* LN1 = (const float*)d_in[1];
    const float* LN2 = (const float*)d_in[2];
    const float* qUs = (const float*)d_in[3];
    const float* qV  = (const float*)d_in[4];
    const float* kUs = (const float*)d_in[5];
    const float* kV  = (const float*)d_in[6];
    const float* vUs = (const float*)d_in[7];
    const float* vV  = (const float*)d_in[8];
    const float* oUs = (const float*)d_in[9];
    const float* oV  = (const float*)d_in[10];
    const float* gUs = (const float*)d_in[11];
    const float* gV  = (const float*)d_in[12];
    const float* uUs = (const float*)d_in[13];
    const float* uV  = (const float*)d_in[14];
    const float* dUs = (const float*)d_in[15];
    const float* dV  = (const float*)d_in[16];
    float* OUT = (float*)d_out;

    char* w = (char*)d_ws;
    bf16*  h1   = (bf16*)(w + 0);          // [1024,4096]
    bf16*  xrq  = (bf16*)(w + 8388608);    // [1024,2048]
    bf16*  xrk  = (bf16*)(w + 12582912);   // [1024,512]
    bf16*  xrv  = (bf16*)(w + 13631488);   // [1024,512]
    bf16*  qb   = (bf16*)(w + 14680064);   // [32,1024,128]
    bf16*  kb   = (bf16*)(w + 23068672);   // [8,1024,128]
    bf16*  vt   = (bf16*)(w + 25165824);   // [8,128,1024]
    float* cs   = (float*)(w + 27262976);  // [1024,64]
    float* sn   = (float*)(w + 27525120);  // [1024,64]
    bf16*  att  = (bf16*)(w + 27787264);   // [1024,4096]
    bf16*  r1   = (bf16*)(w + 36175872);   // [1024,1024]
    bf16*  h2   = (bf16*)(w + 0);
    bf16*  gr   = (bf16*)(w + 8388608);
    bf16*  ur   = (bf16*)(w + 10485760);
    bf16*  hmid = (bf16*)(w + 12582912);   // [1024,14336]
    bf16*  dr   = (bf16*)(w + 41943040);   // [1024,1024]
    const size_t ARENA  = 44040192;
    const size_t PARTSZ = 33554432;
    float* part = (float*)(w + ARENA);

    // bf16 weight arena (after part): element offsets
    bf16* wa = (bf16*)(w + ARENA + PARTSZ);
    const long N_qUs = 262144,  N_qV = 8388608, N_kUs = 65536,  N_kV = 2097152;
    const long N_vUs = 65536,   N_vV = 2097152, N_oUs = 4194304,N_oV = 4194304;
    const long N_gUs = 14680064,N_gV = 4194304, N_uUs = 14680064,N_uV = 4194304;
    const long N_dUs = 4194304, N_dV = 14680064;
    long off = 0;
    bf16* qUsb = wa + off; off += N_qUs;  bf16* qVb = wa + off; off += N_qV;
    bf16* kUsb = wa + off; off += N_kUs;  bf16* kVb = wa + off; off += N_kV;
    bf16* vUsb = wa + off; off += N_vUs;  bf16* vVb = wa + off; off += N_vV;
    bf16* oUsb = wa + off; off += N_oUs;  bf16* oVb = wa + off; off += N_oV;
    bf16* gUsb = wa + off; off += N_gUs;  bf16* gVb = wa + off; off += N_gV;
    bf16* uUsb = wa + off; off += N_uUs;  bf16* uVb = wa + off; off += N_uV;
    bf16* dUsb = wa + off; off += N_dUs;  bf16* dVb = wa + off; off += N_dV;

    const bool med = ws_size >= ARENA + PARTSZ;
    const bool big = ws_size >= ARENA + PARTSZ + (size_t)off * 2;

    dim3 blk(256);

    if (big) {
        CvtArgs ca;
        ca.s[0]=qUs; ca.d[0]=qUsb; ca.n[0]=(int)N_qUs;
        ca.s[1]=qV;  ca.d[1]=qVb;  ca.n[1]=(int)N_qV;
        ca.s[2]=kUs; ca.d[2]=kUsb; ca.n[2]=(int)N_kUs;
        ca.s[3]=kV;  ca.d[3]=kVb;  ca.n[3]=(int)N_kV;
        ca.s[4]=vUs; ca.d[4]=vUsb; ca.n[4]=(int)N_vUs;
        ca.s[5]=vV;  ca.d[5]=vVb;  ca.n[5]=(int)N_vV;
        ca.s[6]=oUs; ca.d[6]=oUsb; ca.n[6]=(int)N_oUs;
        ca.s[7]=oV;  ca.d[7]=oVb;  ca.n[7]=(int)N_oV;
        ca.s[8]=gUs; ca.d[8]=gUsb; ca.n[8]=(int)N_gUs;
        ca.s[9]=gV;  ca.d[9]=gVb;  ca.n[9]=(int)N_gV;
        ca.s[10]=uUs;ca.d[10]=uUsb;ca.n[10]=(int)N_uUs;
        ca.s[11]=uV; ca.d[11]=uVb; ca.n[11]=(int)N_uV;
        ca.s[12]=dUs;ca.d[12]=dUsb;ca.n[12]=(int)N_dUs;
        ca.s[13]=dV; ca.d[13]=dVb; ca.n[13]=(int)N_dV;
        cvt_k<<<2048, blk, 0, stream>>>(ca);

        rmsnorm_k<<<1024, blk, 0, stream>>>(X, LN1, h1);
        // xr_q: K=4096 split 4 -> 512 blocks
        gemm3<EPI_PART><<<dim3(128,1,4), blk, 0, stream>>>(h1,4096,0, qVb,4096,0,nullptr, part,2048,2097152, nullptr, 1024,4, 8);
        reduce_k<<<2048, blk, 0, stream>>>(part, 2097152, 4, xrq);
        // xr_k + xr_v batched (share A=h1), split 4 -> 256 blocks
        gemm3<EPI_PART><<<dim3(32,1,8), blk, 0, stream>>>(h1,4096,0, kVb,4096,0,vVb, part,512,524288, nullptr, 1024,4, 8);
        reduce_k<<<512, blk, 0, stream>>>(part,             524288, 4, xrk);
        reduce_k<<<512, blk, 0, stream>>>(part + 4L*524288, 524288, 4, xrv);

        gemm3<EPI_BF16 ><<<dim3(8,1,32), blk, 0, stream>>>(xrq,2048,64, qUsb,64,8192,nullptr, qb,128,131072, nullptr, 64,1, 8);
        gemm3<EPI_BF16 ><<<dim3(8,1, 8), blk, 0, stream>>>(xrk, 512,64, kUsb,64,8192,nullptr, kb,128,131072, nullptr, 64,1, 8);
        gemm3<EPI_BF16T><<<dim3(8,1, 8), blk, 0, stream>>>(xrv, 512,64, vUsb,64,8192,nullptr, vt,1024,131072, nullptr, 64,1, 8);
        rope_table_k<<<256, blk, 0, stream>>>(cs, sn);
        rope_k<<<8192, blk, 0, stream>>>(qb, cs, sn);
        rope_k<<<2048, blk, 0, stream>>>(kb, cs, sn);
        attn_k<<<dim3(16,32), blk, 0, stream>>>(qb, kb, vt, att);

        gemm3<EPI_PART><<<dim3(64,1,4), blk, 0, stream>>>(att,4096,0, oVb,4096,0,nullptr, part,1024,1048576, nullptr, 1024,4, 8);
        reduce_k<<<1024, blk, 0, stream>>>(part, 1048576, 4, r1);
        gemm3<EPI_F32ADD><<<dim3(256,1,1), blk, 0, stream>>>(r1,1024,0, oUsb,1024,0,nullptr, OUT,4096,0, X, 1024,1, 8);

        rmsnorm_k<<<1024, blk, 0, stream>>>(OUT, LN2, h2);
        gemm3<EPI_PART><<<dim3(64,1,8), blk, 0, stream>>>(h2,4096,0, gVb,4096,0,uVb, part,1024,1048576, nullptr, 1024,4, 8);
        reduce_k<<<1024, blk, 0, stream>>>(part,              1048576, 4, gr);
        reduce_k<<<1024, blk, 0, stream>>>(part + 4L*1048576, 1048576, 4, ur);
        gemm3<EPI_SILU1><<<dim3(896,1,1), blk, 0, stream>>>(gr,1024,0, gUsb,1024,0,nullptr, hmid,14336,0, nullptr, 1024,1, 8);
        gemm3<EPI_MUL  ><<<dim3(896,1,1), blk, 0, stream>>>(ur,1024,0, uUsb,1024,0,nullptr, hmid,14336,0, nullptr, 1024,1, 8);
        gemm3<EPI_PART><<<dim3(64,1,7), blk, 0, stream>>>(hmid,14336,0, dVb,14336,0,nullptr, part,1024,1048576, nullptr, 2048,7, 8);
        reduce_k<<<1024, blk, 0, stream>>>(part, 1048576, 7, dr);
        gemm3<EPI_F32ADD><<<dim3(256,1,1), blk, 0, stream>>>(dr,1024,0, dUsb,1024,0,nullptr, OUT,4096,0, OUT, 1024,1, 8);
        return;
    }

    // ---------------- fallback: round-4 path (fp32-B gemm2) ----------------
    rmsnorm_k<<<1024, blk, 0, stream>>>(X, LN1, h1);
    if (med) {
        gemm2<EPI_PART><<<dim3(8,16,4), blk, 0, stream>>>(h1,4096,0, qV,4096,0,nullptr, part,2048,2097152, nullptr, 1024, 4);
        reduce_k<<<2048, blk, 0, stream>>>(part, 2097152, 4, xrq);
        gemm2<EPI_PART><<<dim3(8,4,8), blk, 0, stream>>>(h1,4096,0, kV,4096,0,vV, part,512,524288, nullptr, 1024, 4);
        reduce_k<<<512, blk, 0, stream>>>(part,             524288, 4, xrk);
        reduce_k<<<512, blk, 0, stream>>>(part + 4L*524288, 524288, 4, xrv);
    } else {
        gemm2<EPI_BF16><<<dim3(8,16,1), blk, 0, stream>>>(h1,4096,0, qV,4096,0,nullptr, xrq,2048,0, nullptr, 4096, 1);
        gemm2<EPI_BF16><<<dim3(8, 4,1), blk, 0, stream>>>(h1,4096,0, kV,4096,0,nullptr, xrk, 512,0, nullptr, 4096, 1);
        gemm2<EPI_BF16><<<dim3(8, 4,1), blk, 0, stream>>>(h1,4096,0, vV,4096,0,nullptr, xrv, 512,0, nullptr, 4096, 1);
    }
    gemm2<EPI_BF16 ><<<dim3(8,1,32), blk, 0, stream>>>(xrq,2048,64, qUs,64,8192,nullptr, qb,128,131072, nullptr, 64, 1);
    gemm2<EPI_BF16 ><<<dim3(8,1, 8), blk, 0, stream>>>(xrk, 512,64, kUs,64,8192,nullptr, kb,128,131072, nullptr, 64, 1);
    gemm2<EPI_BF16T><<<dim3(8,1, 8), blk, 0, stream>>>(xrv, 512,64, vUs,64,8192,nullptr, vt,1024,131072, nullptr, 64, 1);
    rope_table_k<<<256, blk, 0, stream>>>(cs, sn);
    rope_k<<<8192, blk, 0, stream>>>(qb, cs, sn);
    rope_k<<<2048, blk, 0, stream>>>(kb, cs, sn);
    attn_k<<<dim3(16,32), blk, 0, stream>>>(qb, kb, vt, att);
    if (med) {
        gemm2<EPI_PART><<<dim3(8,8,4), blk, 0, stream>>>(att,4096,0, oV,4096,0,nullptr, part,1024,1048576, nullptr, 1024, 4);
        reduce_k<<<1024, blk, 0, stream>>>(part, 1048576, 4, r1);
    } else {
        gemm2<EPI_BF16><<<dim3(8,8,1), blk, 0, stream>>>(att,4096,0, oV,4096,0,nullptr, r1,1024,0, nullptr, 4096, 1);
    }
    gemm2<EPI_F32ADD><<<dim3(8,32,1), blk, 0, stream>>>(r1,1024,0, oUs,1024,0,nullptr, OUT,4096,0, X, 1024, 1);
    rmsnorm_k<<<1024, blk, 0, stream>>>(OUT, LN2, h2);
    if (med) {
        gemm2<EPI_PART><<<dim3(8,8,8), blk, 0, stream>>>(h2,4096,0, gV,4096,0,uV, part,1024,1048576, nullptr, 1024, 4);
        reduce_k<<<1024, blk, 0, stream>>>(part,              1048576, 4, gr);
        reduce_k<<<1024, blk, 0, stream>>>(part + 4L*1048576, 1048576, 4, ur);
    } else {
        gemm2<EPI_BF16><<<dim3(8,8,1), blk, 0, stream>>>(h2,4096,0, gV,4096,0,nullptr, gr,1024,0, nullptr, 4096, 1);
        gemm2<EPI_BF16><<<dim3(8,8,1), blk, 0, stream>>>(h2,4096,0, uV,4096,0,nullptr, ur,1024,0, nullptr, 4096, 1);
    }
    gemm2<EPI_SILU1><<<dim3(8,112,1), blk, 0, stream>>>(gr,1024,0, gUs,1024,0,nullptr, hmid,14336,0, nullptr, 1024, 1);
    gemm2<EPI_MUL  ><<<dim3(8,112,1), blk, 0, stream>>>(ur,1024,0, uUs,1024,0,nullptr, hmid,14336,0, nullptr, 1024, 1);
    if (med) {
        gemm2<EPI_PART><<<dim3(8,8,7), blk, 0, stream>>>(hmid,14336,0, dV,14336,0,nullptr, part,1024,1048576, nullptr, 2048, 7);
        reduce_k<<<1024, blk, 0, stream>>>(part, 1048576, 7, dr);
    } else {
        gemm2<EPI_BF16><<<dim3(8,8,1), blk, 0, stream>>>(hmid,14336,0, dV,14336,0,nullptr, dr,1024,0, nullptr, 14336, 1);
    }
    gemm2<EPI_F32ADD><<<dim3(8,32,1), blk, 0, stream>>>(dr,1024,0, dUs,1024,0,nullptr, OUT,4096,0, OUT, 1024, 1);
}

// Round 6
// 526.508 us; speedup vs baseline: 3.7207x; 1.0843x over previous
//
#include <hip/hip_runtime.h>
#include <math.h>

// ---------------------------------------------------------------------------
// FlashSVD LLaMA block, round 6: kill the 120us cvt_k pass. GEMMs now stage
// fp32 weights DIRECTLY via global_load_lds (32KB fp32 B-tile, 48KB LDS,
// 3 blk/CU) and convert fp32->bf16 at fragment-read time (compiler cvt_pk).
// Both operands source-preswizzled (A: chunk^=row&7; B: chunk16^=row&15),
// matching XOR on ds_read -> ~0 bank conflicts. Everything else unchanged.
// ---------------------------------------------------------------------------

typedef __bf16 bf16;
typedef __bf16 bf16x8 __attribute__((ext_vector_type(8)));
typedef __bf16 bf16x4 __attribute__((ext_vector_type(4)));
typedef float  f32x4  __attribute__((ext_vector_type(4)));

#define EPI_BF16   0
#define EPI_BF16T  1   // transposed bf16 store (V in [d][t] layout)
#define EPI_F32ADD 2   // fp32 store with residual add
#define EPI_SILU1  3   // store silu(acc) bf16
#define EPI_MUL    4   // RMW: C *= acc (bf16)
#define EPI_PART   5   // fp32 partial plane store (split-K)

__device__ __forceinline__ void gld16(const void* g, void* l) {
    __builtin_amdgcn_global_load_lds(
        (const __attribute__((address_space(1))) unsigned int*)g,
        (__attribute__((address_space(3))) unsigned int*)l, 16, 0, 0);
}

// ---------------------------------------------------------------------------
// gemm3f: A bf16 [M,K], B fp32 [N,K], 128x128 tile, BK=64, 4 waves (2x2),
// single-buffered 48KB LDS, 2 barriers/K-step, both operands via gld16.
// Grid: dim3(nwg,1,z); XCD-bijective remap; bm=id%gx, bn=id/gx.
// grid.z = batch*nsplit; zb selects B2 when given (two GEMMs sharing A).
// ---------------------------------------------------------------------------
template<int EPI>
__global__ __launch_bounds__(256)
void gemm3f(const bf16* __restrict__ A, int lda, long sA,
            const float* __restrict__ B, int ldb, long sB, const float* __restrict__ B2,
            void* __restrict__ Cv, int ldc, long sC,
            const float* __restrict__ R, int Kc, int nsplit, int gx)
{
    __shared__ __align__(16) bf16  As[128 * 64];   // 16 KB
    __shared__ __align__(16) float Bs[128 * 64];   // 32 KB

    const int tid = threadIdx.x, lane = tid & 63, w = tid >> 6;
    const int wr = w >> 1, wc = w & 1;

    int id = blockIdx.x;
    {   // bijective XCD remap (m204)
        const int nwg = gridDim.x;
        int q = nwg >> 3, rr = nwg & 7;
        int xcd = id & 7, off = id >> 3;
        id = (xcd < rr ? xcd * (q + 1) : rr * (q + 1) + (xcd - rr) * q) + off;
    }
    const int bm = id % gx, bn = id / gx, bz = blockIdx.z;
    const int ks = bz % nsplit, zb = bz / nsplit;

    const float* Bp = (B2 != nullptr && zb != 0) ? B2 : B;
    const bf16*  Ab = A  + (long)zb * sA + (long)(bm * 128) * lda + (long)ks * Kc;
    const float* Bb = Bp + (long)zb * sB + (long)(bn * 128) * ldb + (long)ks * Kc;

    const int g = lane >> 4, r = lane & 15;
    f32x4 acc[4][4] = {};
    const int nt = Kc >> 6;

    for (int t = 0; t < nt; t++) {
        if (t) __syncthreads();              // all waves done reading LDS(t-1)
        const bf16*  At = Ab + t * 64;
        const float* Bt = Bb + t * 64;
        // A: 1024 16B-chunks (8/row). slot ci holds global chunk (ci&7)^(row&7)
        #pragma unroll
        for (int i = 0; i < 4; i++) {
            int cb = w * 256 + i * 64, ci = cb + lane;
            int row = ci >> 3, col = ((ci & 7) ^ (row & 7)) * 8;
            gld16(At + (long)row * lda + col, &As[cb * 8]);
        }
        // B: 2048 16B-chunks (16/row, 4 floats each). slot ci holds
        // global chunk (ci&15)^(row&15)
        #pragma unroll
        for (int i = 0; i < 8; i++) {
            int cb = w * 512 + i * 64, ci = cb + lane;
            int row = ci >> 4, col = ((ci & 15) ^ (row & 15)) * 4;
            gld16(Bt + (long)row * ldb + col, &Bs[cb * 4]);
        }
        __syncthreads();                     // drains vmcnt -> tile resident
        #pragma unroll
        for (int kk = 0; kk < 2; kk++) {
            bf16x8 af[4], bfr[4];
            #pragma unroll
            for (int m = 0; m < 4; m++) {
                int row = wr * 64 + m * 16 + r;
                af[m] = *(const bf16x8*)&As[row * 64 + (((kk * 4 + g) ^ (row & 7)) * 8)];
            }
            #pragma unroll
            for (int n = 0; n < 4; n++) {
                int row = wc * 64 + n * 16 + r;
                int c0 = kk * 8 + g * 2;
                f32x4 lo = *(const f32x4*)&Bs[row * 64 + (((c0    ) ^ (row & 15)) * 4)];
                f32x4 hi = *(const f32x4*)&Bs[row * 64 + (((c0 + 1) ^ (row & 15)) * 4)];
                bfr[n] = bf16x8{(bf16)lo[0], (bf16)lo[1], (bf16)lo[2], (bf16)lo[3],
                                (bf16)hi[0], (bf16)hi[1], (bf16)hi[2], (bf16)hi[3]};
            }
            #pragma unroll
            for (int m = 0; m < 4; m++)
                #pragma unroll
                for (int n = 0; n < 4; n++)
                    acc[m][n] = __builtin_amdgcn_mfma_f32_16x16x32_bf16(af[m], bfr[n], acc[m][n], 0, 0, 0);
        }
    }

    // epilogue: C layout col = lane&15, row = (lane>>4)*4 + j
    #pragma unroll
    for (int m = 0; m < 4; m++) {
        #pragma unroll
        for (int n = 0; n < 4; n++) {
            const int row0 = bm * 128 + wr * 64 + m * 16 + g * 4;
            const int col  = bn * 128 + wc * 64 + n * 16 + r;
            #pragma unroll
            for (int j = 0; j < 4; j++) {
                float v = acc[m][n][j];
                long row = row0 + j;
                if constexpr (EPI == EPI_BF16) {
                    ((bf16*)Cv)[(long)zb * sC + row * (long)ldc + col] = (bf16)v;
                } else if constexpr (EPI == EPI_BF16T) {
                    ((bf16*)Cv)[(long)zb * sC + (long)col * ldc + row] = (bf16)v;
                } else if constexpr (EPI == EPI_F32ADD) {
                    long idx = row * (long)ldc + col;
                    ((float*)Cv)[idx] = v + R[idx];
                } else if constexpr (EPI == EPI_PART) {
                    ((float*)Cv)[(long)bz * sC + row * (long)ldc + col] = v;
                } else if constexpr (EPI == EPI_SILU1) {
                    ((bf16*)Cv)[row * (long)ldc + col] = (bf16)(v / (1.f + __expf(-v)));
                } else { // EPI_MUL
                    bf16* p = &((bf16*)Cv)[row * (long)ldc + col];
                    *p = (bf16)((float)*p * v);
                }
            }
        }
    }
}

// ---------------------------------------------------------------------------
// gemm2 (fallback for small workspace): fp32 B converted in staging, dbuf.
// ---------------------------------------------------------------------------
template<int EPI>
__global__ __launch_bounds__(256)
void gemm2(const bf16* __restrict__ A, int lda, long sA,
           const float* __restrict__ B, int ldb, long sB, const float* __restrict__ B2,
           void* __restrict__ Cv, int ldc, long sC,
           const float* __restrict__ R, int Kc, int nsplit)
{
    __shared__ __align__(16) bf16 As[2][128 * 64];
    __shared__ __align__(16) bf16 Bs[2][128 * 64];

    const int tid = threadIdx.x, lane = tid & 63, w = tid >> 6;
    const int wr = w >> 1, wc = w & 1;
    const int bm = blockIdx.x, bn = blockIdx.y, bz = blockIdx.z;
    const int ks = bz % nsplit, zb = bz / nsplit;

    const float* Bp = (B2 != nullptr && zb != 0) ? B2 : B;
    const bf16*  Ab = A  + (long)zb * sA + (long)(bm * 128) * lda + (long)ks * Kc;
    const float* Bb = Bp + (long)zb * sB + (long)(bn * 128) * ldb + (long)ks * Kc;

    const int g = lane >> 4, r = lane & 15;
    f32x4 acc[4][4] = {};
    const int nt = Kc >> 6;
    int cur = 0;

    {
        #pragma unroll
        for (int i = 0; i < 4; i++) {
            int cb = i * 256 + w * 64, ci = cb + lane;
            int arow = ci >> 3, acol = ((ci & 7) ^ (arow & 7)) * 8;
            gld16(Ab + (long)arow * lda + acol, &As[0][cb * 8]);
        }
        float4 fb[8];
        #pragma unroll
        for (int i = 0; i < 8; i++) {
            int p = i * 256 + tid;
            fb[i] = *(const float4*)(Bb + (long)(p >> 4) * ldb + (p & 15) * 4);
        }
        #pragma unroll
        for (int i = 0; i < 8; i++) {
            int p = i * 256 + tid, brow = p >> 4, c4 = p & 15;
            bf16x4 h = {(bf16)fb[i].x, (bf16)fb[i].y, (bf16)fb[i].z, (bf16)fb[i].w};
            *(bf16x4*)&Bs[0][brow * 64 + (((c4 >> 1) ^ (brow & 7)) * 8) + (c4 & 1) * 4] = h;
        }
    }
    __syncthreads();

    for (int t = 0; t < nt; t++) {
        float4 fb[8];
        if (t + 1 < nt) {
            const bf16* An = Ab + (t + 1) * 64;
            #pragma unroll
            for (int i = 0; i < 4; i++) {
                int cb = i * 256 + w * 64, ci = cb + lane;
                int arow = ci >> 3, acol = ((ci & 7) ^ (arow & 7)) * 8;
                gld16(An + (long)arow * lda + acol, &As[cur ^ 1][cb * 8]);
            }
            const float* Bn = Bb + (t + 1) * 64;
            #pragma unroll
            for (int i = 0; i < 8; i++) {
                int p = i * 256 + tid;
                fb[i] = *(const float4*)(Bn + (long)(p >> 4) * ldb + (p & 15) * 4);
            }
        }
        #pragma unroll
        for (int kk = 0; kk < 2; kk++) {
            bf16x8 af[4], bfr[4];
            #pragma unroll
            for (int m = 0; m < 4; m++) {
                int row = wr * 64 + m * 16 + r;
                af[m] = *(const bf16x8*)&As[cur][row * 64 + (((kk * 4 + g) ^ (row & 7)) * 8)];
            }
            #pragma unroll
            for (int n = 0; n < 4; n++) {
                int row = wc * 64 + n * 16 + r;
                bfr[n] = *(const bf16x8*)&Bs[cur][row * 64 + (((kk * 4 + g) ^ (row & 7)) * 8)];
            }
            #pragma unroll
            for (int m = 0; m < 4; m++)
                #pragma unroll
                for (int n = 0; n < 4; n++)
                    acc[m][n] = __builtin_amdgcn_mfma_f32_16x16x32_bf16(af[m], bfr[n], acc[m][n], 0, 0, 0);
        }
        if (t + 1 < nt) {
            #pragma unroll
            for (int i = 0; i < 8; i++) {
                int p = i * 256 + tid, brow = p >> 4, c4 = p & 15;
                bf16x4 h = {(bf16)fb[i].x, (bf16)fb[i].y, (bf16)fb[i].z, (bf16)fb[i].w};
                *(bf16x4*)&Bs[cur ^ 1][brow * 64 + (((c4 >> 1) ^ (brow & 7)) * 8) + (c4 & 1) * 4] = h;
            }
            __syncthreads();
            cur ^= 1;
        }
    }

    #pragma unroll
    for (int m = 0; m < 4; m++) {
        #pragma unroll
        for (int n = 0; n < 4; n++) {
            const int row0 = bm * 128 + wr * 64 + m * 16 + g * 4;
            const int col  = bn * 128 + wc * 64 + n * 16 + r;
            #pragma unroll
            for (int j = 0; j < 4; j++) {
                float v = acc[m][n][j];
                long row = row0 + j;
                if constexpr (EPI == EPI_BF16) {
                    ((bf16*)Cv)[(long)zb * sC + row * (long)ldc + col] = (bf16)v;
                } else if constexpr (EPI == EPI_BF16T) {
                    ((bf16*)Cv)[(long)zb * sC + (long)col * ldc + row] = (bf16)v;
                } else if constexpr (EPI == EPI_F32ADD) {
                    long idx = row * (long)ldc + col;
                    ((float*)Cv)[idx] = v + R[idx];
                } else if constexpr (EPI == EPI_PART) {
                    ((float*)Cv)[(long)bz * sC + row * (long)ldc + col] = v;
                } else if constexpr (EPI == EPI_SILU1) {
                    ((bf16*)Cv)[row * (long)ldc + col] = (bf16)(v / (1.f + __expf(-v)));
                } else {
                    bf16* p = &((bf16*)Cv)[row * (long)ldc + col];
                    *p = (bf16)((float)*p * v);
                }
            }
        }
    }
}

// ---------------------------------------------------------------------------
__global__ __launch_bounds__(256)
void reduce_k(const float* __restrict__ part, long pe, int np, bf16* __restrict__ out)
{
    long i = ((long)blockIdx.x * 256 + threadIdx.x) * 4;
    float4 s = *(const float4*)&part[i];
    for (int p = 1; p < np; p++) {
        float4 v = *(const float4*)&part[(long)p * pe + i];
        s.x += v.x; s.y += v.y; s.z += v.z; s.w += v.w;
    }
    bf16x4 o = {(bf16)s.x, (bf16)s.y, (bf16)s.z, (bf16)s.w};
    *(bf16x4*)&out[i] = o;
}

__global__ __launch_bounds__(256)
void rmsnorm_k(const float* __restrict__ x, const float* __restrict__ w,
               bf16* __restrict__ out)
{
    const int D = 4096;
    const long row = blockIdx.x;
    const float* xr = x + row * D;
    float4 v[4];
    float ss = 0.f;
    #pragma unroll
    for (int k = 0; k < 4; k++) {
        v[k] = *(const float4*)&xr[threadIdx.x * 4 + k * 1024];
        ss += v[k].x * v[k].x + v[k].y * v[k].y + v[k].z * v[k].z + v[k].w * v[k].w;
    }
    #pragma unroll
    for (int o = 32; o > 0; o >>= 1) ss += __shfl_down(ss, o);
    __shared__ float red[4];
    if ((threadIdx.x & 63) == 0) red[threadIdx.x >> 6] = ss;
    __syncthreads();
    float rs = rsqrtf((red[0] + red[1] + red[2] + red[3]) / D + 1e-5f);
    #pragma unroll
    for (int k = 0; k < 4; k++) {
        int i = threadIdx.x * 4 + k * 1024;
        float4 wv = *(const float4*)&w[i];
        bf16x4 o4 = {(bf16)(v[k].x * rs * wv.x), (bf16)(v[k].y * rs * wv.y),
                     (bf16)(v[k].z * rs * wv.z), (bf16)(v[k].w * rs * wv.w)};
        *(bf16x4*)&out[row * D + i] = o4;
    }
}

__global__ __launch_bounds__(256)
void rope_table_k(float* cs, float* sn)
{
    int idx = blockIdx.x * blockDim.x + threadIdx.x;  // 1024*64
    int t = idx >> 6, i = idx & 63;
    float inv = powf(10000.0f, -(2.0f * i) / 128.0f);
    float a = (float)t * inv;
    cs[idx] = cosf(a);
    sn[idx] = sinf(a);
}

__global__ __launch_bounds__(256)
void rope_k(bf16* qk, const float* __restrict__ cs, const float* __restrict__ sn)
{
    long idx = (long)blockIdx.x * blockDim.x + threadIdx.x;
    int d = idx & 63;
    long ht = idx >> 6;
    int t = (int)(ht & 1023);
    bf16* p = qk + ht * 128;
    float x1 = (float)p[d], x2 = (float)p[d + 64];
    int i1 = d >> 1;
    float c1 = cs[t * 64 + i1],      s1 = sn[t * 64 + i1];
    float c2 = cs[t * 64 + 32 + i1], s2 = sn[t * 64 + 32 + i1];
    p[d]      = (bf16)(x1 * c1 - x2 * s1);
    p[d + 64] = (bf16)(x2 * c2 + x1 * s2);
}

// ---------------------------------------------------------------------------
// Flash attention (causal, GQA 4:1), 4 waves x 16 q-rows, KV tile 64.
// ---------------------------------------------------------------------------
__global__ __launch_bounds__(256)
void attn_k(const bf16* __restrict__ Q,   // [32][1024][128]
            const bf16* __restrict__ Kb,  // [8][1024][128]
            const bf16* __restrict__ Vt,  // [8][128][1024]
            bf16* __restrict__ O)         // [1024][4096]
{
    const int T = 1024;
    __shared__ __align__(16) bf16 Ks[64][128];
    __shared__ __align__(16) bf16 Vs[128][64];
    __shared__ __align__(16) bf16 Ps[4][16][72];

    const int qt = blockIdx.x, h = blockIdx.y, hk = h >> 2;
    const int tid = threadIdx.x, lane = tid & 63, w = tid >> 6;
    const int g = lane >> 4, r = lane & 15;
    const int qrow0 = qt * 64 + w * 16;

    bf16x8 qf[4];
    const bf16* qp = Q + ((long)h * T + qrow0 + r) * 128;
    #pragma unroll
    for (int dc = 0; dc < 4; dc++) qf[dc] = *(const bf16x8*)(qp + dc * 32 + g * 8);

    f32x4 o_acc[8] = {};
    float m_run[4], l_run[4];
    #pragma unroll
    for (int j = 0; j < 4; j++) { m_run[j] = -1e30f; l_run[j] = 0.f; }

    const float scale = 0.08838834764831845f;
    const int kv_end = qt * 64 + 64;

    for (int kv0 = 0; kv0 < kv_end; kv0 += 64) {
        __syncthreads();
        {
            int tr = tid >> 2;
            const bf16* src = Kb + ((long)hk * T + kv0 + tr) * 128;
            #pragma unroll
            for (int q4 = 0; q4 < 4; q4++) {
                int c = (tid & 3) * 4 + q4;
                bf16x8 v = *(const bf16x8*)(src + c * 8);
                *(bf16x8*)&Ks[tr][(c ^ (tr & 7)) * 8] = v;
            }
        }
        {
            int dd = tid >> 1;
            const bf16* src = Vt + ((long)hk * 128 + dd) * T + kv0;
            #pragma unroll
            for (int q4 = 0; q4 < 4; q4++) {
                int c = (tid & 1) * 4 + q4;
                bf16x8 v = *(const bf16x8*)(src + c * 8);
                *(bf16x8*)&Vs[dd][(c ^ (dd & 7)) * 8] = v;
            }
        }
        __syncthreads();

        f32x4 s[4] = {};
        #pragma unroll
        for (int n = 0; n < 4; n++) {
            int tr = n * 16 + r;
            #pragma unroll
            for (int dc = 0; dc < 4; dc++) {
                int c = (dc * 4 + g) ^ (tr & 7);
                bf16x8 kf = *(const bf16x8*)&Ks[tr][c * 8];
                s[n] = __builtin_amdgcn_mfma_f32_16x16x32_bf16(qf[dc], kf, s[n], 0, 0, 0);
            }
        }

        #pragma unroll
        for (int j = 0; j < 4; j++) {
            int qpos = qrow0 + g * 4 + j;
            float mx = m_run[j];
            #pragma unroll
            for (int n = 0; n < 4; n++) {
                int kpos = kv0 + n * 16 + r;
                float sv = s[n][j] * scale;
                sv = (kpos <= qpos) ? sv : -1e30f;
                s[n][j] = sv;
                mx = fmaxf(mx, sv);
            }
            #pragma unroll
            for (int mask = 1; mask < 16; mask <<= 1) mx = fmaxf(mx, __shfl_xor(mx, mask));
            float corr = __expf(m_run[j] - mx);
            l_run[j] *= corr;
            #pragma unroll
            for (int db = 0; db < 8; db++) o_acc[db][j] *= corr;
            float ls = 0.f;
            #pragma unroll
            for (int n = 0; n < 4; n++) {
                float p = __expf(s[n][j] - mx);
                s[n][j] = p;
                ls += p;
            }
            #pragma unroll
            for (int mask = 1; mask < 16; mask <<= 1) ls += __shfl_xor(ls, mask);
            l_run[j] += ls;
            m_run[j] = mx;
        }

        #pragma unroll
        for (int n = 0; n < 4; n++)
            #pragma unroll
            for (int j = 0; j < 4; j++)
                Ps[w][g * 4 + j][n * 16 + r] = (bf16)s[n][j];
        __syncthreads();

        bf16x8 pf[2];
        #pragma unroll
        for (int kc = 0; kc < 2; kc++)
            pf[kc] = *(const bf16x8*)&Ps[w][r][kc * 32 + g * 8];
        #pragma unroll
        for (int db = 0; db < 8; db++) {
            #pragma unroll
            for (int kc = 0; kc < 2; kc++) {
                int dd = db * 16 + r;
                int c = (kc * 4 + g) ^ (dd & 7);
                bf16x8 vf = *(const bf16x8*)&Vs[dd][c * 8];
                o_acc[db] = __builtin_amdgcn_mfma_f32_16x16x32_bf16(pf[kc], vf, o_acc[db], 0, 0, 0);
            }
        }
    }

    #pragma unroll
    for (int db = 0; db < 8; db++) {
        #pragma unroll
        for (int j = 0; j < 4; j++) {
            int t = qrow0 + g * 4 + j;
            float v = o_acc[db][j] / l_run[j];
            O[(long)t * 4096 + h * 128 + db * 16 + r] = (bf16)v;
        }
    }
}

// ---------------------------------------------------------------------------
extern "C" void kernel_launch(void* const* d_in, const int* in_sizes, int n_in,
                              void* d_out, int out_size, void* d_ws, size_t ws_size,
                              hipStream_t stream)
{
    const float* X   = (const float*)d_in[0];
    const float* LN1 = (const float*)d_in[1];
    const float* LN2 = (const float*)d_in[2];
    const float* qUs = (const float*)d_in[3];
    const float* qV  = (const float*)d_in[4];
    const float* kUs = (const float*)d_in[5];
    const float* kV  = (const float*)d_in[6];
    const float* vUs = (const float*)d_in[7];
    const float* vV  = (const float*)d_in[8];
    const float* oUs = (const float*)d_in[9];
    const float* oV  = (const float*)d_in[10];
    const float* gUs = (const float*)d_in[11];
    const float* gV  = (const float*)d_in[12];
    const float* uUs = (const float*)d_in[13];
    const float* uV  = (const float*)d_in[14];
    const float* dUs = (const float*)d_in[15];
    const float* dV  = (const float*)d_in[16];
    float* OUT = (float*)d_out;

    char* w = (char*)d_ws;
    bf16*  h1   = (bf16*)(w + 0);          // [1024,4096]
    bf16*  xrq  = (bf16*)(w + 8388608);    // [1024,2048]
    bf16*  xrk  = (bf16*)(w + 12582912);   // [1024,512]
    bf16*  xrv  = (bf16*)(w + 13631488);   // [1024,512]
    bf16*  qb   = (bf16*)(w + 14680064);   // [32,1024,128]
    bf16*  kb   = (bf16*)(w + 23068672);   // [8,1024,128]
    bf16*  vt   = (bf16*)(w + 25165824);   // [8,128,1024]
    float* cs   = (float*)(w + 27262976);  // [1024,64]
    float* sn   = (float*)(w + 27525120);  // [1024,64]
    bf16*  att  = (bf16*)(w + 27787264);   // [1024,4096]
    bf16*  r1   = (bf16*)(w + 36175872);   // [1024,1024]
    bf16*  h2   = (bf16*)(w + 0);
    bf16*  gr   = (bf16*)(w + 8388608);
    bf16*  ur   = (bf16*)(w + 10485760);
    bf16*  hmid = (bf16*)(w + 12582912);   // [1024,14336]
    bf16*  dr   = (bf16*)(w + 41943040);   // [1024,1024]
    const size_t ARENA  = 44040192;
    const size_t PARTSZ = 33554432;
    float* part = (float*)(w + ARENA);
    const bool med = ws_size >= ARENA + PARTSZ;

    dim3 blk(256);

    if (med) {
        rmsnorm_k<<<1024, blk, 0, stream>>>(X, LN1, h1);
        // xr_q: K=4096 split 4 -> 512 blocks
        gemm3f<EPI_PART><<<dim3(128,1,4), blk, 0, stream>>>(h1,4096,0, qV,4096,0,nullptr, part,2048,2097152, nullptr, 1024,4, 8);
        reduce_k<<<2048, blk, 0, stream>>>(part, 2097152, 4, xrq);
        // xr_k + xr_v batched (share A=h1), split 4 -> 256 blocks
        gemm3f<EPI_PART><<<dim3(32,1,8), blk, 0, stream>>>(h1,4096,0, kV,4096,0,vV, part,512,524288, nullptr, 1024,4, 8);
        reduce_k<<<512, blk, 0, stream>>>(part,             524288, 4, xrk);
        reduce_k<<<512, blk, 0, stream>>>(part + 4L*524288, 524288, 4, xrv);

        gemm3f<EPI_BF16 ><<<dim3(8,1,32), blk, 0, stream>>>(xrq,2048,64, qUs,64,8192,nullptr, qb,128,131072, nullptr, 64,1, 8);
        gemm3f<EPI_BF16 ><<<dim3(8,1, 8), blk, 0, stream>>>(xrk, 512,64, kUs,64,8192,nullptr, kb,128,131072, nullptr, 64,1, 8);
        gemm3f<EPI_BF16T><<<dim3(8,1, 8), blk, 0, stream>>>(xrv, 512,64, vUs,64,8192,nullptr, vt,1024,131072, nullptr, 64,1, 8);
        rope_table_k<<<256, blk, 0, stream>>>(cs, sn);
        rope_k<<<8192, blk, 0, stream>>>(qb, cs, sn);
        rope_k<<<2048, blk, 0, stream>>>(kb, cs, sn);
        attn_k<<<dim3(16,32), blk, 0, stream>>>(qb, kb, vt, att);

        gemm3f<EPI_PART><<<dim3(64,1,4), blk, 0, stream>>>(att,4096,0, oV,4096,0,nullptr, part,1024,1048576, nullptr, 1024,4, 8);
        reduce_k<<<1024, blk, 0, stream>>>(part, 1048576, 4, r1);
        gemm3f<EPI_F32ADD><<<dim3(256,1,1), blk, 0, stream>>>(r1,1024,0, oUs,1024,0,nullptr, OUT,4096,0, X, 1024,1, 8);

        rmsnorm_k<<<1024, blk, 0, stream>>>(OUT, LN2, h2);
        gemm3f<EPI_PART><<<dim3(64,1,8), blk, 0, stream>>>(h2,4096,0, gV,4096,0,uV, part,1024,1048576, nullptr, 1024,4, 8);
        reduce_k<<<1024, blk, 0, stream>>>(part,              1048576, 4, gr);
        reduce_k<<<1024, blk, 0, stream>>>(part + 4L*1048576, 1048576, 4, ur);
        gemm3f<EPI_SILU1><<<dim3(896,1,1), blk, 0, stream>>>(gr,1024,0, gUs,1024,0,nullptr, hmid,14336,0, nullptr, 1024,1, 8);
        gemm3f<EPI_MUL  ><<<dim3(896,1,1), blk, 0, stream>>>(ur,1024,0, uUs,1024,0,nullptr, hmid,14336,0, nullptr, 1024,1, 8);
        gemm3f<EPI_PART><<<dim3(64,1,7), blk, 0, stream>>>(hmid,14336,0, dV,14336,0,nullptr, part,1024,1048576, nullptr, 2048,7, 8);
        reduce_k<<<1024, blk, 0, stream>>>(part, 1048576, 7, dr);
        gemm3f<EPI_F32ADD><<<dim3(256,1,1), blk, 0, stream>>>(dr,1024,0, dUs,1024,0,nullptr, OUT,4096,0, OUT, 1024,1, 8);
        return;
    }

    // ---------------- fallback: gemm2 (fp32-B dbuf) path ----------------
    rmsnorm_k<<<1024, blk, 0, stream>>>(X, LN1, h1);
    gemm2<EPI_BF16><<<dim3(8,16,1), blk, 0, stream>>>(h1,4096,0, qV,4096,0,nullptr, xrq,2048,0, nullptr, 4096, 1);
    gemm2<EPI_BF16><<<dim3(8, 4,1), blk, 0, stream>>>(h1,4096,0, kV,4096,0,nullptr, xrk, 512,0, nullptr, 4096, 1);
    gemm2<EPI_BF16><<<dim3(8, 4,1), blk, 0, stream>>>(h1,4096,0, vV,4096,0,nullptr, xrv, 512,0, nullptr, 4096, 1);
    gemm2<EPI_BF16 ><<<dim3(8,1,32), blk, 0, stream>>>(xrq,2048,64, qUs,64,8192,nullptr, qb,128,131072, nullptr, 64, 1);
    gemm2<EPI_BF16 ><<<dim3(8,1, 8), blk, 0, stream>>>(xrk, 512,64, kUs,64,8192,nullptr, kb,128,131072, nullptr, 64, 1);
    gemm2<EPI_BF16T><<<dim3(8,1, 8), blk, 0, stream>>>(xrv, 512,64, vUs,64,8192,nullptr, vt,1024,131072, nullptr, 64, 1);
    rope_table_k<<<256, blk, 0, stream>>>(cs, sn);
    rope_k<<<8192, blk, 0, stream>>>(qb, cs, sn);
    rope_k<<<2048, blk, 0, stream>>>(kb, cs, sn);
    attn_k<<<dim3(16,32), blk, 0, stream>>>(qb, kb, vt, att);
    gemm2<EPI_BF16><<<dim3(8,8,1), blk, 0, stream>>>(att,4096,0, oV,4096,0,nullptr, r1,1024,0, nullptr, 4096, 1);
    gemm2<EPI_F32ADD><<<dim3(8,32,1), blk, 0, stream>>>(r1,1024,0, oUs,1024,0,nullptr, OUT,4096,0, X, 1024, 1);
    rmsnorm_k<<<1024, blk, 0, stream>>>(OUT, LN2, h2);
    gemm2<EPI_BF16><<<dim3(8,8,1), blk, 0, stream>>>(h2,4096,0, gV,4096,0,nullptr, gr,1024,0, nullptr, 4096, 1);
    gemm2<EPI_BF16><<<dim3(8,8,1), blk, 0, stream>>>(h2,4096,0, uV,4096,0,nullptr, ur,1024,0, nullptr, 4096, 1);
    gemm2<EPI_SILU1><<<dim3(8,112,1), blk, 0, stream>>>(gr,1024,0, gUs,1024,0,nullptr, hmid,14336,0, nullptr, 1024, 1);
    gemm2<EPI_MUL  ><<<dim3(8,112,1), blk, 0, stream>>>(ur,1024,0, uUs,1024,0,nullptr, hmid,14336,0, nullptr, 1024, 1);
    gemm2<EPI_BF16><<<dim3(8,8,1), blk, 0, stream>>>(hmid,14336,0, dV,14336,0,nullptr, dr,1024,0, nullptr, 14336, 1);
    gemm2<EPI_F32ADD><<<dim3(8,32,1), blk, 0, stream>>>(dr,1024,0, dUs,1024,0,nullptr, OUT,4096,0, OUT, 1024, 1);
}